// Round 14
// baseline (327.818 us; speedup 1.0000x reference)
//
#include <hip/hip_runtime.h>
#include <hip/hip_fp16.h>
#include <math.h>

#define G_GRAPHS 64
#define BIN_SHIFT 7
#define BIN_SIZE 128
#define NBINS_CAP 1024      // supports n <= 131072 (src fits 17 bits)
#define C_CHUNK 16384       // cblocks must be <= 256 (nE <= 4.19M)
#define CAP 4608            // max staged edges per bin held in LDS

typedef unsigned short usv8 __attribute__((ext_vector_type(8)));

__device__ __forceinline__ void fma4(float4& a, float s, float4 w) {
    a.x += s * w.x; a.y += s * w.y; a.z += s * w.z; a.w += s * w.w;
}
__device__ __forceinline__ void add4(float4& a, float4 b) {
    a.x += b.x; a.y += b.y; a.z += b.z; a.w += b.w;
}
__device__ __forceinline__ float4 h4_to_f4(ushort4 u) {
    return make_float4(__half2float(__ushort_as_half(u.x)),
                       __half2float(__ushort_as_half(u.y)),
                       __half2float(__ushort_as_half(u.z)),
                       __half2float(__ushort_as_half(u.w)));
}
__device__ __forceinline__ ushort4 f4_to_h4(float4 f) {
    ushort4 u;
    u.x = __half_as_ushort(__float2half_rn(f.x));
    u.y = __half_as_ushort(__float2half_rn(f.y));
    u.z = __half_as_ushort(__float2half_rn(f.z));
    u.w = __half_as_ushort(__float2half_rn(f.w));
    return u;
}
__device__ __forceinline__ usv8 f4x2_to_h8(float4 a, float4 b) {
    usv8 r;
    r.s0 = __half_as_ushort(__float2half_rn(a.x));
    r.s1 = __half_as_ushort(__float2half_rn(a.y));
    r.s2 = __half_as_ushort(__float2half_rn(a.z));
    r.s3 = __half_as_ushort(__float2half_rn(a.w));
    r.s4 = __half_as_ushort(__float2half_rn(b.x));
    r.s5 = __half_as_ushort(__float2half_rn(b.y));
    r.s6 = __half_as_ushort(__float2half_rn(b.z));
    r.s7 = __half_as_ushort(__float2half_rn(b.w));
    return r;
}

// ---------------- fp8 e4m3 (OCP) pack/unpack ----------------
__device__ __forceinline__ float4 fp8x4_to_f4(unsigned int w) {
#if __has_builtin(__builtin_amdgcn_cvt_f32_fp8)
    float4 r;
    r.x = __builtin_amdgcn_cvt_f32_fp8((int)w, 0);
    r.y = __builtin_amdgcn_cvt_f32_fp8((int)w, 1);
    r.z = __builtin_amdgcn_cvt_f32_fp8((int)w, 2);
    r.w = __builtin_amdgcn_cvt_f32_fp8((int)w, 3);
    return r;
#else
    const float sc = 1.329227995784916e+36f;   // 2^120
    unsigned b0 = w & 0xffu, b1 = (w >> 8) & 0xffu,
             b2 = (w >> 16) & 0xffu, b3 = (w >> 24) & 0xffu;
    float4 r;
    r.x = __uint_as_float(((b0 & 0x80u) << 24) | ((b0 & 0x7fu) << 20)) * sc;
    r.y = __uint_as_float(((b1 & 0x80u) << 24) | ((b1 & 0x7fu) << 20)) * sc;
    r.z = __uint_as_float(((b2 & 0x80u) << 24) | ((b2 & 0x7fu) << 20)) * sc;
    r.w = __uint_as_float(((b3 & 0x80u) << 24) | ((b3 & 0x7fu) << 20)) * sc;
    return r;
#endif
}
__device__ __forceinline__ unsigned int f4_to_fp8x4(float4 f) {
#if __has_builtin(__builtin_amdgcn_cvt_pk_fp8_f32)
    int v = __builtin_amdgcn_cvt_pk_fp8_f32(f.x, f.y, 0, false);
    v = __builtin_amdgcn_cvt_pk_fp8_f32(f.z, f.w, v, true);
    return (unsigned int)v;
#else
    const float sc = 7.52316384526264e-37f;    // 2^-120
    float vv[4] = {f.x, f.y, f.z, f.w};
    unsigned out = 0;
    #pragma unroll
    for (int i = 0; i < 4; ++i) {
        unsigned u = __float_as_uint(vv[i] * sc);
        unsigned s = (u >> 24) & 0x80u;
        u += 0x00080000u;
        unsigned m = (u >> 20) & 0x7fu;
        out |= (s | m) << (8 * i);
    }
    return out;
#endif
}

// ---- g1A: fused gemm1 (blocks < tiles64) and binA (blocks >= tiles64) ----
__global__ __launch_bounds__(256) void k_g1A(
    const float* __restrict__ x, const float* __restrict__ w1a,
    unsigned int* __restrict__ y8, int n, int tiles64,
    const int* __restrict__ dst, int* __restrict__ hist, int nE, int nbins,
    int vec4ok)
{
    __shared__ float  xs[64 * 129];
    __shared__ float4 ws[128 * 16];
    __shared__ int    cnt[NBINS_CAP];
    int tid = threadIdx.x;
    if (blockIdx.x < tiles64) {
        const float4* w4 = (const float4*)w1a;
        #pragma unroll
        for (int i = tid; i < 128 * 16; i += 256) ws[i] = w4[i];
        int row0 = blockIdx.x * 64;
        for (int i = tid; i < 64 * 32; i += 256) {
            int r = i >> 5, k4 = i & 31;
            float4 v = {0.f, 0.f, 0.f, 0.f};
            if (row0 + r < n) v = ((const float4*)x)[(size_t)(row0 + r) * 32 + k4];
            xs[r * 129 + k4 * 4 + 0] = v.x;
            xs[r * 129 + k4 * 4 + 1] = v.y;
            xs[r * 129 + k4 * 4 + 2] = v.z;
            xs[r * 129 + k4 * 4 + 3] = v.w;
        }
        __syncthreads();
        int c4 = tid & 15, rg = tid >> 4;
        float4 acc[4] = {{0,0,0,0},{0,0,0,0},{0,0,0,0},{0,0,0,0}};
        const float* xr = xs + rg * 4 * 129;
        #pragma unroll 8
        for (int k = 0; k < 128; ++k) {
            float4 wv = ws[k * 16 + c4];
            fma4(acc[0], xr[k +   0], wv);
            fma4(acc[1], xr[k + 129], wv);
            fma4(acc[2], xr[k + 258], wv);
            fma4(acc[3], xr[k + 387], wv);
        }
        #pragma unroll
        for (int i = 0; i < 4; ++i) {
            int row = row0 + rg * 4 + i;
            if (row < n) y8[(size_t)row * 16 + c4] = f4_to_fp8x4(acc[i]);
        }
    } else {
        int blk = blockIdx.x - tiles64;
        for (int i = tid; i < nbins; i += 256) cnt[i] = 0;
        __syncthreads();
        int base = blk * C_CHUNK;
        int end  = min(base + C_CHUNK, nE);
        int done = base;
        if (vec4ok) {
            int cnt4 = (end - base) >> 2;
            const int4* d4 = (const int4*)(dst + base);
            for (int i = tid; i < cnt4; i += 256) {
                int4 v = d4[i];
                atomicAdd(&cnt[v.x >> BIN_SHIFT], 1);
                atomicAdd(&cnt[v.y >> BIN_SHIFT], 1);
                atomicAdd(&cnt[v.z >> BIN_SHIFT], 1);
                atomicAdd(&cnt[v.w >> BIN_SHIFT], 1);
            }
            done = base + (cnt4 << 2);
        }
        for (int e = done + tid; e < end; e += 256)
            atomicAdd(&cnt[dst[e] >> BIN_SHIFT], 1);
        __syncthreads();
        int* hrow = hist + (size_t)blk * nbins;
        for (int i = tid; i < nbins; i += 256) hrow[i] = cnt[i];
    }
}

// ---- binB1: per bin, exclusive-scan hist column across blocks; binCnt = total
__global__ __launch_bounds__(256) void k_binB1(
    int* __restrict__ hist, int cblocks, int nbins, int* __restrict__ binCnt)
{
    __shared__ int sb[256];
    int b = blockIdx.x;
    int t = threadIdx.x;
    int v = (t < cblocks) ? hist[(size_t)t * nbins + b] : 0;
    sb[t] = v;
    __syncthreads();
    for (int d = 1; d < 256; d <<= 1) {
        int tt = (t >= d) ? sb[t - d] : 0;
        __syncthreads();
        sb[t] += tt;
        __syncthreads();
    }
    if (t < cblocks) hist[(size_t)t * nbins + b] = sb[t] - v;
    if (t == 0) binCnt[b] = sb[255];
}

// ---- binB2: scan binCnt -> binOff ----
__global__ __launch_bounds__(1024) void k_binB2(
    const int* __restrict__ binCnt, int nbins, int nE, int* __restrict__ binOff)
{
    __shared__ int sb[1024];
    int tid = threadIdx.x;
    int v = (tid < nbins) ? binCnt[tid] : 0;
    sb[tid] = v;
    __syncthreads();
    for (int d = 1; d < 1024; d <<= 1) {
        int t = (tid >= d) ? sb[tid - d] : 0;
        __syncthreads();
        sb[tid] += t;
        __syncthreads();
    }
    if (tid < nbins) binOff[tid] = sb[tid] - v;
    if (tid == 0) binOff[nbins] = nE;
}

// ---- binC2: single pass — load per-block bases, scatter with LDS cursor ----
__global__ __launch_bounds__(256) void k_binC2(
    const int* __restrict__ src, const int* __restrict__ dst,
    const int* __restrict__ binOff, const int* __restrict__ hist,
    int* __restrict__ staging, int nE, int nbins, int vec4ok)
{
    __shared__ int cnt[NBINS_CAP];
    const int* hrow = hist + (size_t)blockIdx.x * nbins;
    for (int i = threadIdx.x; i < nbins; i += 256)
        cnt[i] = binOff[i] + hrow[i];
    __syncthreads();
    int base = blockIdx.x * C_CHUNK;
    int end  = min(base + C_CHUNK, nE);
    int done = base;
    if (vec4ok) {
        int cnt4 = (end - base) >> 2;
        const int4* d4 = (const int4*)(dst + base);
        const int4* s4 = (const int4*)(src + base);
        for (int i = threadIdx.x; i < cnt4; i += 256) {
            int4 dv = d4[i]; int4 sv = s4[i];
            int b, p;
            b = dv.x >> BIN_SHIFT; p = atomicAdd(&cnt[b], 1);
            staging[p] = ((dv.x & (BIN_SIZE-1)) << 17) | sv.x;
            b = dv.y >> BIN_SHIFT; p = atomicAdd(&cnt[b], 1);
            staging[p] = ((dv.y & (BIN_SIZE-1)) << 17) | sv.y;
            b = dv.z >> BIN_SHIFT; p = atomicAdd(&cnt[b], 1);
            staging[p] = ((dv.z & (BIN_SIZE-1)) << 17) | sv.z;
            b = dv.w >> BIN_SHIFT; p = atomicAdd(&cnt[b], 1);
            staging[p] = ((dv.w & (BIN_SIZE-1)) << 17) | sv.w;
        }
        done = base + (cnt4 << 2);
    }
    for (int e = done + threadIdx.x; e < end; e += 256) {
        int d = dst[e], s = src[e];
        int b = d >> BIN_SHIFT;
        int p = atomicAdd(&cnt[b], 1);
        staging[p] = ((d & (BIN_SIZE - 1)) << 17) | s;
    }
}

// ---- agg1: one block per bin; LDS list build (split by src-half); two-phase
//      gather so each phase's table half (3.2MB) is L2-resident grid-wide.
__global__ __launch_bounds__(512) void k_agg1(
    const unsigned int* __restrict__ y8, const int* __restrict__ binOff,
    const int* __restrict__ staging, int* __restrict__ csr_fb,
    const float* __restrict__ b1a, const float* __restrict__ eps1p,
    __half* __restrict__ h1, int n,
    float* __restrict__ p_sum, float* __restrict__ p_sq)
{
    __shared__ int   stage_s[CAP];            // reused as fp16 partials after sort
    __shared__ int   lcsr_s[CAP];
    __shared__ int   degA[BIN_SIZE], degT[BIN_SIZE];
    __shared__ int   start_[BIN_SIZE], curA[BIN_SIZE], curB[BIN_SIZE];
    __shared__ float s_sum[8][64], s_sq[8][64];
    usv8* acch = (usv8*)stage_s;              // 128*8 entries = 16KB <= 18KB

    int b = blockIdx.x;
    int s = binOff[b], e = binOff[b + 1];
    int cntE = e - s;
    int tid = threadIdx.x;
    bool fits = (cntE <= CAP);
    int nHalf = n >> 1;

    if (tid < BIN_SIZE) { degA[tid] = 0; degT[tid] = 0; }
    __syncthreads();
    for (int j = tid; j < cntE; j += 512) {
        int pk = staging[s + j];
        if (fits) stage_s[j] = pk;
        int ln = pk >> 17;
        atomicAdd(&degT[ln], 1);
        if ((pk & 0x1FFFF) < nHalf) atomicAdd(&degA[ln], 1);
    }
    __syncthreads();
    if (tid < BIN_SIZE) curA[tid] = degT[tid];
    __syncthreads();
    for (int d = 1; d < BIN_SIZE; d <<= 1) {
        int t = (tid >= d && tid < BIN_SIZE) ? curA[tid - d] : 0;
        __syncthreads();
        if (tid < BIN_SIZE) curA[tid] += t;
        __syncthreads();
    }
    if (tid < BIN_SIZE) {
        int st = curA[tid] - degT[tid];
        start_[tid] = st;
        curA[tid] = st;
        curB[tid] = st + degA[tid];
    }
    __syncthreads();
    int* lcsr = fits ? lcsr_s : (csr_fb + s);
    for (int j = tid; j < cntE; j += 512) {
        int pk = fits ? stage_s[j] : staging[s + j];
        int ln = pk >> 17, sv = pk & 0x1FFFF;
        int p = (sv < nHalf) ? atomicAdd(&curA[ln], 1) : atomicAdd(&curB[ln], 1);
        lcsr[p] = sv;
    }
    __syncthreads();   // stage_s now dead -> acch reuse

    int wave = tid >> 6, lane = tid & 63;
    int c = lane & 7, g = lane >> 3;   // 8 lanes x uint2; 8 edge streams
    const uint2* y82 = (const uint2*)y8;
    float ep = 1.0f + eps1p[0];
    float4 bv0 = ((const float4*)b1a)[c * 2];
    float4 bv1 = ((const float4*)b1a)[c * 2 + 1];
    int node0 = b * BIN_SIZE;

    // ---------------- phase A: src < nHalf (lower half of table) ----------
    for (int k = 0; k < 16; ++k) {
        int ln = wave * 16 + k;
        int node = node0 + ln;
        if (node >= n) break;
        int o  = start_[ln];
        int eA = o + degA[ln];
        float4 aLo = {0,0,0,0}, aHi = {0,0,0,0};
        if (g == 0) {
            uint2 v = y82[(size_t)node * 8 + c];
            float4 lo = fp8x4_to_f4(v.x), hi = fp8x4_to_f4(v.y);
            aLo.x = ep * lo.x + bv0.x; aLo.y = ep * lo.y + bv0.y;
            aLo.z = ep * lo.z + bv0.z; aLo.w = ep * lo.w + bv0.w;
            aHi.x = ep * hi.x + bv1.x; aHi.y = ep * hi.y + bv1.y;
            aHi.z = ep * hi.z + bv1.z; aHi.w = ep * hi.w + bv1.w;
        }
        int j = o + g;
        for (; j + 8 < eA; j += 16) {
            int s0 = lcsr[j], s1 = lcsr[j + 8];
            uint2 w0 = y82[(size_t)s0 * 8 + c];
            uint2 w1 = y82[(size_t)s1 * 8 + c];
            add4(aLo, fp8x4_to_f4(w0.x)); add4(aHi, fp8x4_to_f4(w0.y));
            add4(aLo, fp8x4_to_f4(w1.x)); add4(aHi, fp8x4_to_f4(w1.y));
        }
        for (; j < eA; j += 8) {
            uint2 w = y82[(size_t)lcsr[j] * 8 + c];
            add4(aLo, fp8x4_to_f4(w.x)); add4(aHi, fp8x4_to_f4(w.y));
        }
        #pragma unroll
        for (int d = 8; d < 64; d <<= 1) {
            aLo.x += __shfl_xor(aLo.x, d, 64); aLo.y += __shfl_xor(aLo.y, d, 64);
            aLo.z += __shfl_xor(aLo.z, d, 64); aLo.w += __shfl_xor(aLo.w, d, 64);
            aHi.x += __shfl_xor(aHi.x, d, 64); aHi.y += __shfl_xor(aHi.y, d, 64);
            aHi.z += __shfl_xor(aHi.z, d, 64); aHi.w += __shfl_xor(aHi.w, d, 64);
        }
        if (g == 0) acch[ln * 8 + c] = f4x2_to_h8(aLo, aHi);
    }
    __syncthreads();

    // ---------------- phase B: src >= nHalf (upper half) ------------------
    float rs[8] = {0,0,0,0,0,0,0,0}, rq[8] = {0,0,0,0,0,0,0,0};
    for (int k = 0; k < 16; ++k) {
        int ln = wave * 16 + k;
        int node = node0 + ln;
        if (node >= n) break;
        int o  = start_[ln];
        int eA = o + degA[ln];
        int eT = o + degT[ln];
        float4 aLo = {0,0,0,0}, aHi = {0,0,0,0};
        int j = eA + g;
        for (; j + 8 < eT; j += 16) {
            int s0 = lcsr[j], s1 = lcsr[j + 8];
            uint2 w0 = y82[(size_t)s0 * 8 + c];
            uint2 w1 = y82[(size_t)s1 * 8 + c];
            add4(aLo, fp8x4_to_f4(w0.x)); add4(aHi, fp8x4_to_f4(w0.y));
            add4(aLo, fp8x4_to_f4(w1.x)); add4(aHi, fp8x4_to_f4(w1.y));
        }
        for (; j < eT; j += 8) {
            uint2 w = y82[(size_t)lcsr[j] * 8 + c];
            add4(aLo, fp8x4_to_f4(w.x)); add4(aHi, fp8x4_to_f4(w.y));
        }
        #pragma unroll
        for (int d = 8; d < 64; d <<= 1) {
            aLo.x += __shfl_xor(aLo.x, d, 64); aLo.y += __shfl_xor(aLo.y, d, 64);
            aLo.z += __shfl_xor(aLo.z, d, 64); aLo.w += __shfl_xor(aLo.w, d, 64);
            aHi.x += __shfl_xor(aHi.x, d, 64); aHi.y += __shfl_xor(aHi.y, d, 64);
            aHi.z += __shfl_xor(aHi.z, d, 64); aHi.w += __shfl_xor(aHi.w, d, 64);
        }
        if (g == 0) {
            usv8 ph = acch[ln * 8 + c];
            aLo.x += __half2float(__ushort_as_half(ph.s0));
            aLo.y += __half2float(__ushort_as_half(ph.s1));
            aLo.z += __half2float(__ushort_as_half(ph.s2));
            aLo.w += __half2float(__ushort_as_half(ph.s3));
            aHi.x += __half2float(__ushort_as_half(ph.s4));
            aHi.y += __half2float(__ushort_as_half(ph.s5));
            aHi.z += __half2float(__ushort_as_half(ph.s6));
            aHi.w += __half2float(__ushort_as_half(ph.s7));
            ((usv8*)h1)[(size_t)node * 8 + c] = f4x2_to_h8(aLo, aHi);
            rs[0] += aLo.x; rq[0] += aLo.x * aLo.x;
            rs[1] += aLo.y; rq[1] += aLo.y * aLo.y;
            rs[2] += aLo.z; rq[2] += aLo.z * aLo.z;
            rs[3] += aLo.w; rq[3] += aLo.w * aLo.w;
            rs[4] += aHi.x; rq[4] += aHi.x * aHi.x;
            rs[5] += aHi.y; rq[5] += aHi.y * aHi.y;
            rs[6] += aHi.z; rq[6] += aHi.z * aHi.z;
            rs[7] += aHi.w; rq[7] += aHi.w * aHi.w;
        }
    }
    if (g == 0) {
        #pragma unroll
        for (int i = 0; i < 8; ++i) {
            s_sum[wave][8 * c + i] = rs[i];
            s_sq[wave][8 * c + i]  = rq[i];
        }
    }
    __syncthreads();
    if (tid < 64) {
        float ssum = 0.f, ssq = 0.f;
        #pragma unroll
        for (int w = 0; w < 8; ++w) { ssum += s_sum[w][tid]; ssq += s_sq[w][tid]; }
        int ps = (b & 63) * 64 + tid;
        atomicAdd(&p_sum[ps], ssum);
        atomicAdd(&p_sq[ps], ssq);
    }
}

// ---- agg2: one block per bin; LDS list build; single-phase gather --------
__global__ __launch_bounds__(512) void k_agg2(
    const unsigned int* __restrict__ h28, const int* __restrict__ binOff,
    const int* __restrict__ staging, int* __restrict__ csr_fb,
    const float* __restrict__ eps2p, __half* __restrict__ agg2h, int n)
{
    __shared__ int stage_s[CAP];
    __shared__ int lcsr_s[CAP];
    __shared__ int degT[BIN_SIZE], start_[BIN_SIZE], cur[BIN_SIZE];
    int b = blockIdx.x;
    int s = binOff[b], e = binOff[b + 1];
    int cntE = e - s;
    int tid = threadIdx.x;
    bool fits = (cntE <= CAP);
    if (tid < BIN_SIZE) degT[tid] = 0;
    __syncthreads();
    for (int j = tid; j < cntE; j += 512) {
        int pk = staging[s + j];
        if (fits) stage_s[j] = pk;
        atomicAdd(&degT[pk >> 17], 1);
    }
    __syncthreads();
    if (tid < BIN_SIZE) cur[tid] = degT[tid];
    __syncthreads();
    for (int d = 1; d < BIN_SIZE; d <<= 1) {
        int t = (tid >= d && tid < BIN_SIZE) ? cur[tid - d] : 0;
        __syncthreads();
        if (tid < BIN_SIZE) cur[tid] += t;
        __syncthreads();
    }
    if (tid < BIN_SIZE) {
        int st = cur[tid] - degT[tid];
        start_[tid] = st;
        cur[tid] = st;
    }
    __syncthreads();
    int* lcsr = fits ? lcsr_s : (csr_fb + s);
    for (int j = tid; j < cntE; j += 512) {
        int pk = fits ? stage_s[j] : staging[s + j];
        int p = atomicAdd(&cur[pk >> 17], 1);
        lcsr[p] = pk & 0x1FFFF;
    }
    __syncthreads();

    int wave = tid >> 6, lane = tid & 63;
    int c = lane & 3, g = lane >> 2;   // 4 lanes x uint2; 16 edge streams
    const uint2* h282 = (const uint2*)h28;
    float ep = 1.0f + eps2p[0];
    int node0 = b * BIN_SIZE;
    for (int k = 0; k < 16; ++k) {
        int ln = wave * 16 + k;
        int node = node0 + ln;
        if (node >= n) break;
        int o = start_[ln], eT = o + degT[ln];
        float4 aLo = {0,0,0,0}, aHi = {0,0,0,0};
        if (g == 0) {
            uint2 v = h282[(size_t)node * 4 + c];
            float4 lo = fp8x4_to_f4(v.x), hi = fp8x4_to_f4(v.y);
            aLo.x = ep * lo.x; aLo.y = ep * lo.y; aLo.z = ep * lo.z; aLo.w = ep * lo.w;
            aHi.x = ep * hi.x; aHi.y = ep * hi.y; aHi.z = ep * hi.z; aHi.w = ep * hi.w;
        }
        int j = o + g;
        for (; j + 16 < eT; j += 32) {
            int s0 = lcsr[j], s1 = lcsr[j + 16];
            uint2 w0 = h282[(size_t)s0 * 4 + c];
            uint2 w1 = h282[(size_t)s1 * 4 + c];
            add4(aLo, fp8x4_to_f4(w0.x)); add4(aHi, fp8x4_to_f4(w0.y));
            add4(aLo, fp8x4_to_f4(w1.x)); add4(aHi, fp8x4_to_f4(w1.y));
        }
        for (; j < eT; j += 16) {
            uint2 w = h282[(size_t)lcsr[j] * 4 + c];
            add4(aLo, fp8x4_to_f4(w.x)); add4(aHi, fp8x4_to_f4(w.y));
        }
        #pragma unroll
        for (int d = 4; d < 64; d <<= 1) {
            aLo.x += __shfl_xor(aLo.x, d, 64); aLo.y += __shfl_xor(aLo.y, d, 64);
            aLo.z += __shfl_xor(aLo.z, d, 64); aLo.w += __shfl_xor(aLo.w, d, 64);
            aHi.x += __shfl_xor(aHi.x, d, 64); aHi.y += __shfl_xor(aHi.y, d, 64);
            aHi.z += __shfl_xor(aHi.z, d, 64); aHi.w += __shfl_xor(aHi.w, d, 64);
        }
        if (g == 0)
            ((usv8*)agg2h)[(size_t)node * 4 + c] = f4x2_to_h8(aLo, aHi);
    }
}

// ---------------- fold BN into affine (reduces 64 partial slots) ----------
__global__ void k_bnfin(const float* __restrict__ p_sum, const float* __restrict__ p_sq,
                        const float* __restrict__ gamma, const float* __restrict__ beta,
                        float nf, float* __restrict__ a, float* __restrict__ c)
{
    int i = threadIdx.x;   // 64
    float s = 0.f, q = 0.f;
    for (int k = 0; k < 64; ++k) { s += p_sum[k*64 + i]; q += p_sq[k*64 + i]; }
    float mu  = s / nf;
    float var = q / nf - mu * mu;
    float av  = gamma[i] * rsqrtf(var + 1e-5f);
    a[i] = av;
    c[i] = beta[i] - av * mu;
}

// ---- mlp1b: h28(fp8) = relu(a1*h1+c1) @ w1b + b1b  (h1 fp16) ----
__global__ __launch_bounds__(256) void k_mlp1b(
    const __half* __restrict__ h1, const float* __restrict__ a1,
    const float* __restrict__ c1, const float* __restrict__ w1b,
    const float* __restrict__ b1b, unsigned int* __restrict__ h28, int n)
{
    __shared__ float  xs[128 * 65];
    __shared__ float4 ws[64 * 8];
    __shared__ float  as[64], cs[64];
    int tid = threadIdx.x;
    #pragma unroll
    for (int i = tid; i < 64 * 8; i += 256) ws[i] = ((const float4*)w1b)[i];
    if (tid < 64) { as[tid] = a1[tid]; cs[tid] = c1[tid]; }
    __syncthreads();
    int row0 = blockIdx.x * 128;
    for (int i = tid; i < 128 * 16; i += 256) {
        int r = i >> 4, k4 = i & 15;
        float4 v = {0.f, 0.f, 0.f, 0.f};
        if (row0 + r < n) {
            v = h4_to_f4(((const ushort4*)h1)[(size_t)(row0 + r) * 16 + k4]);
            v.x = fmaxf(as[k4*4+0] * v.x + cs[k4*4+0], 0.f);
            v.y = fmaxf(as[k4*4+1] * v.y + cs[k4*4+1], 0.f);
            v.z = fmaxf(as[k4*4+2] * v.z + cs[k4*4+2], 0.f);
            v.w = fmaxf(as[k4*4+3] * v.w + cs[k4*4+3], 0.f);
        }
        xs[r * 65 + k4 * 4 + 0] = v.x;
        xs[r * 65 + k4 * 4 + 1] = v.y;
        xs[r * 65 + k4 * 4 + 2] = v.z;
        xs[r * 65 + k4 * 4 + 3] = v.w;
    }
    __syncthreads();
    int c4 = tid & 7, rg = tid >> 3;
    float4 bv = ((const float4*)b1b)[c4];
    float4 acc[4] = {bv, bv, bv, bv};
    const float* xr = xs + rg * 4 * 65;
    #pragma unroll 8
    for (int k = 0; k < 64; ++k) {
        float4 wv = ws[k * 8 + c4];
        fma4(acc[0], xr[k +   0], wv);
        fma4(acc[1], xr[k +  65], wv);
        fma4(acc[2], xr[k + 130], wv);
        fma4(acc[3], xr[k + 195], wv);
    }
    #pragma unroll
    for (int i = 0; i < 4; ++i) {
        int row = row0 + rg * 4 + i;
        if (row < n) h28[(size_t)row * 8 + c4] = f4_to_fp8x4(acc[i]);
    }
}

// ---- gemm2: h3(fp16) = agg2h(fp16) @ w2a + b2a ; fused BN2 partial stats ----
__global__ __launch_bounds__(256) void k_gemm2(
    const __half* __restrict__ agg2h, const float* __restrict__ w2a,
    const float* __restrict__ b2a, __half* __restrict__ h3, int n,
    float* __restrict__ p_sum, float* __restrict__ p_sq)
{
    __shared__ float  xs[64 * 33];
    __shared__ float4 ws[32 * 16];
    __shared__ float  s_sum[64], s_sq[64];
    int tid = threadIdx.x;
    if (tid < 64) { s_sum[tid] = 0.f; s_sq[tid] = 0.f; }
    #pragma unroll
    for (int i = tid; i < 32 * 16; i += 256) ws[i] = ((const float4*)w2a)[i];
    int row0 = blockIdx.x * 64;
    for (int i = tid; i < 64 * 8; i += 256) {
        int r = i >> 3, k4 = i & 7;
        float4 v = {0.f, 0.f, 0.f, 0.f};
        if (row0 + r < n) v = h4_to_f4(((const ushort4*)agg2h)[(size_t)(row0 + r) * 8 + k4]);
        xs[r * 33 + k4 * 4 + 0] = v.x;
        xs[r * 33 + k4 * 4 + 1] = v.y;
        xs[r * 33 + k4 * 4 + 2] = v.z;
        xs[r * 33 + k4 * 4 + 3] = v.w;
    }
    __syncthreads();
    int c4 = tid & 15, rg = tid >> 4;
    float4 bv = ((const float4*)b2a)[c4];
    float4 acc[4] = {bv, bv, bv, bv};
    const float* xr = xs + rg * 4 * 33;
    #pragma unroll
    for (int k = 0; k < 32; ++k) {
        float4 wv = ws[k * 16 + c4];
        fma4(acc[0], xr[k +  0], wv);
        fma4(acc[1], xr[k + 33], wv);
        fma4(acc[2], xr[k + 66], wv);
        fma4(acc[3], xr[k + 99], wv);
    }
    float cs_[4] = {0,0,0,0}, cq_[4] = {0,0,0,0};
    #pragma unroll
    for (int i = 0; i < 4; ++i) {
        int row = row0 + rg * 4 + i;
        if (row < n) {
            ((ushort4*)h3)[(size_t)row * 16 + c4] = f4_to_h4(acc[i]);
            cs_[0] += acc[i].x; cq_[0] += acc[i].x * acc[i].x;
            cs_[1] += acc[i].y; cq_[1] += acc[i].y * acc[i].y;
            cs_[2] += acc[i].z; cq_[2] += acc[i].z * acc[i].z;
            cs_[3] += acc[i].w; cq_[3] += acc[i].w * acc[i].w;
        }
    }
    #pragma unroll
    for (int jj = 0; jj < 4; ++jj) {
        atomicAdd(&s_sum[c4 * 4 + jj], cs_[jj]);
        atomicAdd(&s_sq[c4 * 4 + jj],  cq_[jj]);
    }
    __syncthreads();
    if (tid < 64) {
        int ps = (blockIdx.x & 63) * 64 + tid;
        atomicAdd(&p_sum[ps], s_sum[tid]);
        atomicAdd(&p_sq[ps],  s_sq[tid]);
    }
}

// ---- final: h4 = relu(a2*h3+c2) @ w2b + b2b ; pool per graph (h3 fp16) ----
__global__ __launch_bounds__(256) void k_final(
    const __half* __restrict__ h3, const float* __restrict__ a2,
    const float* __restrict__ c2, const float* __restrict__ w2b,
    const float* __restrict__ b2b, const int* __restrict__ batch,
    float* __restrict__ pool, float* __restrict__ cnt, int n)
{
    __shared__ float  xs[64 * 65];
    __shared__ float4 ws[64 * 4];
    __shared__ float  as[64], cs[64];
    __shared__ float  pl[G_GRAPHS * 16];
    __shared__ float  cl[G_GRAPHS];
    int tid = threadIdx.x;
    for (int i = tid; i < 256; i += 256) ws[i] = ((const float4*)w2b)[i];
    if (tid < 64) { as[tid] = a2[tid]; cs[tid] = c2[tid]; cl[tid] = 0.f; }
    for (int i = tid; i < G_GRAPHS * 16; i += 256) pl[i] = 0.f;
    __syncthreads();
    int row0 = blockIdx.x * 64;
    for (int i = tid; i < 64 * 16; i += 256) {
        int r = i >> 4, k4 = i & 15;
        float4 v = {0.f, 0.f, 0.f, 0.f};
        if (row0 + r < n) {
            v = h4_to_f4(((const ushort4*)h3)[(size_t)(row0 + r) * 16 + k4]);
            v.x = fmaxf(as[k4*4+0] * v.x + cs[k4*4+0], 0.f);
            v.y = fmaxf(as[k4*4+1] * v.y + cs[k4*4+1], 0.f);
            v.z = fmaxf(as[k4*4+2] * v.z + cs[k4*4+2], 0.f);
            v.w = fmaxf(as[k4*4+3] * v.w + cs[k4*4+3], 0.f);
        }
        xs[r * 65 + k4 * 4 + 0] = v.x;
        xs[r * 65 + k4 * 4 + 1] = v.y;
        xs[r * 65 + k4 * 4 + 2] = v.z;
        xs[r * 65 + k4 * 4 + 3] = v.w;
    }
    __syncthreads();
    int c4 = tid & 3, r = tid >> 2;
    float4 acc = ((const float4*)b2b)[c4];
    const float* xr = xs + r * 65;
    #pragma unroll 8
    for (int k = 0; k < 64; ++k) {
        float4 wv = ws[k * 4 + c4];
        fma4(acc, xr[k], wv);
    }
    int row = row0 + r;
    if (row < n) {
        int g = batch[row];
        if (c4 == 0) atomicAdd(&cl[g], 1.f);
        float* pp = &pl[g * 16 + c4 * 4];
        atomicAdd(pp + 0, acc.x); atomicAdd(pp + 1, acc.y);
        atomicAdd(pp + 2, acc.z); atomicAdd(pp + 3, acc.w);
    }
    __syncthreads();
    if (tid < 64 && cl[tid] != 0.f) atomicAdd(&cnt[tid], cl[tid]);
    for (int i = tid; i < G_GRAPHS * 16; i += 256) {
        int g = i >> 4;
        if (cl[g] != 0.f) atomicAdd(&pool[i], pl[i]);
    }
}

// ---------------- head ----------------
__global__ void k_head(const float* __restrict__ pool, const float* __restrict__ cnt,
                       const float* __restrict__ lw, const float* __restrict__ lb,
                       float* __restrict__ out)
{
    int g = threadIdx.x;
    float cv = fmaxf(cnt[g], 1.0f);
    float acc = lb[0];
    #pragma unroll
    for (int f = 0; f < 16; ++f) acc += (pool[g * 16 + f] / cv) * lw[f];
    out[g] = 1.0f / (1.0f + expf(-acc));
}

extern "C" void kernel_launch(void* const* d_in, const int* in_sizes, int n_in,
                              void* d_out, int out_size, void* d_ws, size_t ws_size,
                              hipStream_t stream)
{
    const float* x    = (const float*)d_in[0];
    const int*   eidx = (const int*)d_in[1];
    const int*   batch= (const int*)d_in[2];
    const float* eps1 = (const float*)d_in[3];
    const float* eps2 = (const float*)d_in[4];
    const float* w1a  = (const float*)d_in[5];
    const float* b1a  = (const float*)d_in[6];
    const float* g1   = (const float*)d_in[7];
    const float* bt1  = (const float*)d_in[8];
    const float* w1b  = (const float*)d_in[9];
    const float* b1b  = (const float*)d_in[10];
    const float* w2a  = (const float*)d_in[11];
    const float* b2a  = (const float*)d_in[12];
    const float* g2   = (const float*)d_in[13];
    const float* bt2  = (const float*)d_in[14];
    const float* w2b  = (const float*)d_in[15];
    const float* b2b  = (const float*)d_in[16];
    const float* lw   = (const float*)d_in[17];
    const float* lb   = (const float*)d_in[18];
    float* out = (float*)d_out;

    int n  = in_sizes[0] / 128;
    int nE = in_sizes[1] / 2;
    const int* srcI = eidx;
    const int* dstI = eidx + nE;
    int vec4ok = ((nE & 3) == 0) && ((((uintptr_t)eidx) & 15) == 0);

    char* wsb = (char*)d_ws;
    size_t nn = (size_t)n;
    unsigned int* y8  = (unsigned int*)wsb;             // n*64 fp8
    __half* h1        = (__half*)(wsb + nn * 64);       // n*64 fp16 (reused as h3)
    unsigned int* h28 = (unsigned int*)(wsb + nn * 192);// n*32 fp8
    __half* agg2h     = (__half*)(wsb + nn * 224);      // n*32 fp16
    __half* h3        = h1;                              // alias (h1 dead after mlp1b)
    float* stats = (float*)(wsb + nn * 288);
    float* a1     = stats;          float* c1     = stats + 64;
    float* a2     = stats + 128;    float* c2     = stats + 192;
    float* pool   = stats + 256;    float* cntb   = stats + 1280;
    float* p_sum1 = stats + 1344;   float* p_sq1  = stats + 5440;
    float* p_sum2 = stats + 9536;   float* p_sq2  = stats + 13632;
    // stats region total: 17728 floats

    int cblocks = (nE + C_CHUNK - 1) / C_CHUNK;   // must be <= 256
    int nbins   = (n + BIN_SIZE - 1) >> BIN_SHIFT;

    int* binCnt  = (int*)(stats + 17728);        // NBINS_CAP+1
    int* binOff  = binCnt + NBINS_CAP + 1;       // NBINS_CAP+1
    int* staging = binOff + NBINS_CAP + 1;       // nE
    int* hist    = staging + nE;                 // cblocks * nbins
    int* csr_fb  = hist + (size_t)cblocks * nbins;  // nE (fallback only)

    hipMemsetAsync(stats + 256, 0, (17728 - 256) * sizeof(float), stream);

    int tiles64  = (n + 63) / 64;
    int tiles128 = (n + 127) / 128;

    k_g1A<<<tiles64 + cblocks, 256, 0, stream>>>(x, w1a, y8, n, tiles64,
                                                 dstI, hist, nE, nbins, vec4ok);
    k_binB1<<<nbins, 256, 0, stream>>>(hist, cblocks, nbins, binCnt);
    k_binB2<<<1, 1024, 0, stream>>>(binCnt, nbins, nE, binOff);
    k_binC2<<<cblocks, 256, 0, stream>>>(srcI, dstI, binOff, hist, staging, nE, nbins, vec4ok);

    k_agg1<<<nbins, 512, 0, stream>>>(y8, binOff, staging, csr_fb, b1a, eps1, h1, n, p_sum1, p_sq1);
    k_bnfin<<<1, 64, 0, stream>>>(p_sum1, p_sq1, g1, bt1, (float)n, a1, c1);
    k_mlp1b<<<tiles128, 256, 0, stream>>>(h1, a1, c1, w1b, b1b, h28, n);
    k_agg2<<<nbins, 512, 0, stream>>>(h28, binOff, staging, csr_fb, eps2, agg2h, n);
    k_gemm2<<<tiles64, 256, 0, stream>>>(agg2h, w2a, b2a, h3, n, p_sum2, p_sq2);
    k_bnfin<<<1, 64, 0, stream>>>(p_sum2, p_sq2, g2, bt2, (float)n, a2, c2);
    k_final<<<tiles64, 256, 0, stream>>>(h3, a2, c2, w2b, b2b, batch, pool, cntb, n);
    k_head<<<1, 64, 0, stream>>>(pool, cntb, lw, lb, out);
}

// Round 15
// 307.586 us; speedup vs baseline: 1.0658x; 1.0658x over previous
//
#include <hip/hip_runtime.h>
#include <hip/hip_fp16.h>
#include <math.h>

#define G_GRAPHS 64
#define BIN_SHIFT 7
#define BIN_SIZE 128
#define NBINS_CAP 1024      // supports n <= 131072 (src fits 17 bits)
#define C_CHUNK 16384       // cblocks must be <= 256 (nE <= 4.19M)

typedef unsigned short usv8 __attribute__((ext_vector_type(8)));

__device__ __forceinline__ void fma4(float4& a, float s, float4 w) {
    a.x += s * w.x; a.y += s * w.y; a.z += s * w.z; a.w += s * w.w;
}
__device__ __forceinline__ void add4(float4& a, float4 b) {
    a.x += b.x; a.y += b.y; a.z += b.z; a.w += b.w;
}
__device__ __forceinline__ float4 h4_to_f4(ushort4 u) {
    return make_float4(__half2float(__ushort_as_half(u.x)),
                       __half2float(__ushort_as_half(u.y)),
                       __half2float(__ushort_as_half(u.z)),
                       __half2float(__ushort_as_half(u.w)));
}
__device__ __forceinline__ ushort4 f4_to_h4(float4 f) {
    ushort4 u;
    u.x = __half_as_ushort(__float2half_rn(f.x));
    u.y = __half_as_ushort(__float2half_rn(f.y));
    u.z = __half_as_ushort(__float2half_rn(f.z));
    u.w = __half_as_ushort(__float2half_rn(f.w));
    return u;
}
__device__ __forceinline__ usv8 f4x2_to_h8(float4 a, float4 b) {
    usv8 r;
    r.s0 = __half_as_ushort(__float2half_rn(a.x));
    r.s1 = __half_as_ushort(__float2half_rn(a.y));
    r.s2 = __half_as_ushort(__float2half_rn(a.z));
    r.s3 = __half_as_ushort(__float2half_rn(a.w));
    r.s4 = __half_as_ushort(__float2half_rn(b.x));
    r.s5 = __half_as_ushort(__float2half_rn(b.y));
    r.s6 = __half_as_ushort(__float2half_rn(b.z));
    r.s7 = __half_as_ushort(__float2half_rn(b.w));
    return r;
}

// ---------------- fp8 e4m3 (OCP) pack/unpack ----------------
__device__ __forceinline__ float4 fp8x4_to_f4(unsigned int w) {
#if __has_builtin(__builtin_amdgcn_cvt_f32_fp8)
    float4 r;
    r.x = __builtin_amdgcn_cvt_f32_fp8((int)w, 0);
    r.y = __builtin_amdgcn_cvt_f32_fp8((int)w, 1);
    r.z = __builtin_amdgcn_cvt_f32_fp8((int)w, 2);
    r.w = __builtin_amdgcn_cvt_f32_fp8((int)w, 3);
    return r;
#else
    const float sc = 1.329227995784916e+36f;   // 2^120
    unsigned b0 = w & 0xffu, b1 = (w >> 8) & 0xffu,
             b2 = (w >> 16) & 0xffu, b3 = (w >> 24) & 0xffu;
    float4 r;
    r.x = __uint_as_float(((b0 & 0x80u) << 24) | ((b0 & 0x7fu) << 20)) * sc;
    r.y = __uint_as_float(((b1 & 0x80u) << 24) | ((b1 & 0x7fu) << 20)) * sc;
    r.z = __uint_as_float(((b2 & 0x80u) << 24) | ((b2 & 0x7fu) << 20)) * sc;
    r.w = __uint_as_float(((b3 & 0x80u) << 24) | ((b3 & 0x7fu) << 20)) * sc;
    return r;
#endif
}
__device__ __forceinline__ unsigned int f4_to_fp8x4(float4 f) {
#if __has_builtin(__builtin_amdgcn_cvt_pk_fp8_f32)
    int v = __builtin_amdgcn_cvt_pk_fp8_f32(f.x, f.y, 0, false);
    v = __builtin_amdgcn_cvt_pk_fp8_f32(f.z, f.w, v, true);
    return (unsigned int)v;
#else
    const float sc = 7.52316384526264e-37f;    // 2^-120
    float vv[4] = {f.x, f.y, f.z, f.w};
    unsigned out = 0;
    #pragma unroll
    for (int i = 0; i < 4; ++i) {
        unsigned u = __float_as_uint(vv[i] * sc);
        unsigned s = (u >> 24) & 0x80u;
        u += 0x00080000u;
        unsigned m = (u >> 20) & 0x7fu;
        out |= (s | m) << (8 * i);
    }
    return out;
#endif
}

// ---- g1A: fused gemm1 (blocks < tiles64) and binA (blocks >= tiles64) ----
__global__ __launch_bounds__(256) void k_g1A(
    const float* __restrict__ x, const float* __restrict__ w1a,
    unsigned int* __restrict__ y8, int n, int tiles64,
    const int* __restrict__ dst, int* __restrict__ hist, int nE, int nbins,
    int vec4ok)
{
    __shared__ float  xs[64 * 129];
    __shared__ float4 ws[128 * 16];
    __shared__ int    cnt[NBINS_CAP];
    int tid = threadIdx.x;
    if (blockIdx.x < tiles64) {
        const float4* w4 = (const float4*)w1a;
        #pragma unroll
        for (int i = tid; i < 128 * 16; i += 256) ws[i] = w4[i];
        int row0 = blockIdx.x * 64;
        for (int i = tid; i < 64 * 32; i += 256) {
            int r = i >> 5, k4 = i & 31;
            float4 v = {0.f, 0.f, 0.f, 0.f};
            if (row0 + r < n) v = ((const float4*)x)[(size_t)(row0 + r) * 32 + k4];
            xs[r * 129 + k4 * 4 + 0] = v.x;
            xs[r * 129 + k4 * 4 + 1] = v.y;
            xs[r * 129 + k4 * 4 + 2] = v.z;
            xs[r * 129 + k4 * 4 + 3] = v.w;
        }
        __syncthreads();
        int c4 = tid & 15, rg = tid >> 4;
        float4 acc[4] = {{0,0,0,0},{0,0,0,0},{0,0,0,0},{0,0,0,0}};
        const float* xr = xs + rg * 4 * 129;
        #pragma unroll 8
        for (int k = 0; k < 128; ++k) {
            float4 wv = ws[k * 16 + c4];
            fma4(acc[0], xr[k +   0], wv);
            fma4(acc[1], xr[k + 129], wv);
            fma4(acc[2], xr[k + 258], wv);
            fma4(acc[3], xr[k + 387], wv);
        }
        #pragma unroll
        for (int i = 0; i < 4; ++i) {
            int row = row0 + rg * 4 + i;
            if (row < n) y8[(size_t)row * 16 + c4] = f4_to_fp8x4(acc[i]);
        }
    } else {
        int blk = blockIdx.x - tiles64;
        for (int i = tid; i < nbins; i += 256) cnt[i] = 0;
        __syncthreads();
        int base = blk * C_CHUNK;
        int end  = min(base + C_CHUNK, nE);
        int done = base;
        if (vec4ok) {
            int cnt4 = (end - base) >> 2;
            const int4* d4 = (const int4*)(dst + base);
            for (int i = tid; i < cnt4; i += 256) {
                int4 v = d4[i];
                atomicAdd(&cnt[v.x >> BIN_SHIFT], 1);
                atomicAdd(&cnt[v.y >> BIN_SHIFT], 1);
                atomicAdd(&cnt[v.z >> BIN_SHIFT], 1);
                atomicAdd(&cnt[v.w >> BIN_SHIFT], 1);
            }
            done = base + (cnt4 << 2);
        }
        for (int e = done + tid; e < end; e += 256)
            atomicAdd(&cnt[dst[e] >> BIN_SHIFT], 1);
        __syncthreads();
        int* hrow = hist + (size_t)blk * nbins;
        for (int i = tid; i < nbins; i += 256) hrow[i] = cnt[i];
    }
}

// ---- binB1: per bin, exclusive-scan hist column across blocks ----
__global__ __launch_bounds__(256) void k_binB1(
    int* __restrict__ hist, int cblocks, int nbins, int* __restrict__ binCnt)
{
    __shared__ int sb[256];
    int b = blockIdx.x;
    int t = threadIdx.x;
    int v = (t < cblocks) ? hist[(size_t)t * nbins + b] : 0;
    sb[t] = v;
    __syncthreads();
    for (int d = 1; d < 256; d <<= 1) {
        int tt = (t >= d) ? sb[t - d] : 0;
        __syncthreads();
        sb[t] += tt;
        __syncthreads();
    }
    if (t < cblocks) hist[(size_t)t * nbins + b] = sb[t] - v;
    if (t == 0) binCnt[b] = sb[255];
}

// ---- binB2: scan binCnt -> binOff; off[n]=nE ----
__global__ __launch_bounds__(1024) void k_binB2(
    const int* __restrict__ binCnt, int nbins, int nE,
    int* __restrict__ binOff, int* __restrict__ off, int n)
{
    __shared__ int sb[1024];
    int tid = threadIdx.x;
    int v = (tid < nbins) ? binCnt[tid] : 0;
    sb[tid] = v;
    __syncthreads();
    for (int d = 1; d < 1024; d <<= 1) {
        int t = (tid >= d) ? sb[tid - d] : 0;
        __syncthreads();
        sb[tid] += t;
        __syncthreads();
    }
    if (tid < nbins) binOff[tid] = sb[tid] - v;
    if (tid == 0) { binOff[nbins] = nE; off[n] = nE; }
}

// ---- binC2: single pass — load per-block bases, scatter with LDS cursor ----
__global__ __launch_bounds__(256) void k_binC2(
    const int* __restrict__ src, const int* __restrict__ dst,
    const int* __restrict__ binOff, const int* __restrict__ hist,
    int* __restrict__ staging, int nE, int nbins, int vec4ok)
{
    __shared__ int cnt[NBINS_CAP];
    const int* hrow = hist + (size_t)blockIdx.x * nbins;
    for (int i = threadIdx.x; i < nbins; i += 256)
        cnt[i] = binOff[i] + hrow[i];
    __syncthreads();
    int base = blockIdx.x * C_CHUNK;
    int end  = min(base + C_CHUNK, nE);
    int done = base;
    if (vec4ok) {
        int cnt4 = (end - base) >> 2;
        const int4* d4 = (const int4*)(dst + base);
        const int4* s4 = (const int4*)(src + base);
        for (int i = threadIdx.x; i < cnt4; i += 256) {
            int4 dv = d4[i]; int4 sv = s4[i];
            int b, p;
            b = dv.x >> BIN_SHIFT; p = atomicAdd(&cnt[b], 1);
            staging[p] = ((dv.x & (BIN_SIZE-1)) << 17) | sv.x;
            b = dv.y >> BIN_SHIFT; p = atomicAdd(&cnt[b], 1);
            staging[p] = ((dv.y & (BIN_SIZE-1)) << 17) | sv.y;
            b = dv.z >> BIN_SHIFT; p = atomicAdd(&cnt[b], 1);
            staging[p] = ((dv.z & (BIN_SIZE-1)) << 17) | sv.z;
            b = dv.w >> BIN_SHIFT; p = atomicAdd(&cnt[b], 1);
            staging[p] = ((dv.w & (BIN_SIZE-1)) << 17) | sv.w;
        }
        done = base + (cnt4 << 2);
    }
    for (int e = done + threadIdx.x; e < end; e += 256) {
        int d = dst[e], s = src[e];
        int b = d >> BIN_SHIFT;
        int p = atomicAdd(&cnt[b], 1);
        staging[p] = ((d & (BIN_SIZE - 1)) << 17) | s;
    }
}

__global__ __launch_bounds__(256) void k_binD(
    const int* __restrict__ binOff, const int* __restrict__ staging,
    int* __restrict__ off, int* __restrict__ csr, int n)
{
    __shared__ int deg[BIN_SIZE];
    __shared__ int cur[BIN_SIZE];
    int b = blockIdx.x;
    int s = binOff[b], e = binOff[b + 1];
    int tid = threadIdx.x;
    if (tid < BIN_SIZE) deg[tid] = 0;
    __syncthreads();
    for (int j = s + tid; j < e; j += 256)
        atomicAdd(&deg[staging[j] >> 17], 1);
    __syncthreads();
    if (tid < BIN_SIZE) cur[tid] = deg[tid];
    __syncthreads();
    for (int d = 1; d < BIN_SIZE; d <<= 1) {
        int t = (tid >= d && tid < BIN_SIZE) ? cur[tid - d] : 0;
        __syncthreads();
        if (tid < BIN_SIZE) cur[tid] += t;
        __syncthreads();
    }
    if (tid < BIN_SIZE) {
        int node = b * BIN_SIZE + tid;
        int ex = s + cur[tid] - deg[tid];
        if (node < n) off[node] = ex;
        cur[tid] = ex;
    }
    __syncthreads();
    for (int j = s + tid; j < e; j += 256) {
        int pk = staging[j];
        int p = atomicAdd(&cur[pk >> 17], 1);
        csr[p] = pk & 0x1FFFF;
    }
}

// ---- agg1: h1(fp16)[d] = (1+eps1)*y[d] + b1a + sum_{src} y[src]  (y fp8)
//      4 lanes x uint4 (16B) cover a 64B row; 16 edge streams
__global__ __launch_bounds__(256) void k_agg1(
    const unsigned int* __restrict__ y8, const int* __restrict__ off,
    const int* __restrict__ csr, const float* __restrict__ b1a,
    const float* __restrict__ eps1p, __half* __restrict__ h1, int n,
    float* __restrict__ p_sum, float* __restrict__ p_sq)
{
    __shared__ float s_sum[4][64];
    __shared__ float s_sq[4][64];
    int slot = threadIdx.x >> 6;
    int lane = threadIdx.x & 63;
    int node = blockIdx.x * 4 + slot;
    int c = lane & 3;      // uint4 column (16 bytes each)
    int g = lane >> 2;     // 0..15 edge streams
    bool valid = node < n;
    int o = 0, e = 0;
    if (valid) { o = off[node]; e = off[node + 1]; }
    const uint4* y84 = (const uint4*)y8;
    float4 q0 = {0,0,0,0}, q1 = {0,0,0,0}, q2 = {0,0,0,0}, q3 = {0,0,0,0};
    if (valid && g == 0) {
        uint4 v = y84[(size_t)node * 4 + c];
        float4 f0 = fp8x4_to_f4(v.x), f1 = fp8x4_to_f4(v.y);
        float4 f2 = fp8x4_to_f4(v.z), f3 = fp8x4_to_f4(v.w);
        float4 b0 = ((const float4*)b1a)[c * 4];
        float4 b1 = ((const float4*)b1a)[c * 4 + 1];
        float4 b2 = ((const float4*)b1a)[c * 4 + 2];
        float4 b3 = ((const float4*)b1a)[c * 4 + 3];
        float ep = 1.0f + eps1p[0];
        q0.x = ep*f0.x + b0.x; q0.y = ep*f0.y + b0.y; q0.z = ep*f0.z + b0.z; q0.w = ep*f0.w + b0.w;
        q1.x = ep*f1.x + b1.x; q1.y = ep*f1.y + b1.y; q1.z = ep*f1.z + b1.z; q1.w = ep*f1.w + b1.w;
        q2.x = ep*f2.x + b2.x; q2.y = ep*f2.y + b2.y; q2.z = ep*f2.z + b2.z; q2.w = ep*f2.w + b2.w;
        q3.x = ep*f3.x + b3.x; q3.y = ep*f3.y + b3.y; q3.z = ep*f3.z + b3.z; q3.w = ep*f3.w + b3.w;
    }
    int j = o + g;
    for (; j + 16 < e; j += 32) {
        int s0 = csr[j], s1 = csr[j + 16];
        uint4 w0 = y84[(size_t)s0 * 4 + c];
        uint4 w1 = y84[(size_t)s1 * 4 + c];
        add4(q0, fp8x4_to_f4(w0.x)); add4(q1, fp8x4_to_f4(w0.y));
        add4(q2, fp8x4_to_f4(w0.z)); add4(q3, fp8x4_to_f4(w0.w));
        add4(q0, fp8x4_to_f4(w1.x)); add4(q1, fp8x4_to_f4(w1.y));
        add4(q2, fp8x4_to_f4(w1.z)); add4(q3, fp8x4_to_f4(w1.w));
    }
    for (; j < e; j += 16) {
        uint4 w = y84[(size_t)csr[j] * 4 + c];
        add4(q0, fp8x4_to_f4(w.x)); add4(q1, fp8x4_to_f4(w.y));
        add4(q2, fp8x4_to_f4(w.z)); add4(q3, fp8x4_to_f4(w.w));
    }
    #pragma unroll
    for (int d = 4; d < 64; d <<= 1) {
        q0.x += __shfl_xor(q0.x, d, 64); q0.y += __shfl_xor(q0.y, d, 64);
        q0.z += __shfl_xor(q0.z, d, 64); q0.w += __shfl_xor(q0.w, d, 64);
        q1.x += __shfl_xor(q1.x, d, 64); q1.y += __shfl_xor(q1.y, d, 64);
        q1.z += __shfl_xor(q1.z, d, 64); q1.w += __shfl_xor(q1.w, d, 64);
        q2.x += __shfl_xor(q2.x, d, 64); q2.y += __shfl_xor(q2.y, d, 64);
        q2.z += __shfl_xor(q2.z, d, 64); q2.w += __shfl_xor(q2.w, d, 64);
        q3.x += __shfl_xor(q3.x, d, 64); q3.y += __shfl_xor(q3.y, d, 64);
        q3.z += __shfl_xor(q3.z, d, 64); q3.w += __shfl_xor(q3.w, d, 64);
    }
    if (g == 0) {
        if (valid) {
            ((usv8*)h1)[(size_t)node * 8 + c * 2]     = f4x2_to_h8(q0, q1);
            ((usv8*)h1)[(size_t)node * 8 + c * 2 + 1] = f4x2_to_h8(q2, q3);
        }
        float vv[16] = {q0.x,q0.y,q0.z,q0.w, q1.x,q1.y,q1.z,q1.w,
                        q2.x,q2.y,q2.z,q2.w, q3.x,q3.y,q3.z,q3.w};
        #pragma unroll
        for (int i = 0; i < 16; ++i) {
            float v = valid ? vv[i] : 0.f;
            s_sum[slot][c * 16 + i] = v;
            s_sq[slot][c * 16 + i]  = v * v;
        }
    }
    __syncthreads();
    if (threadIdx.x < 64) {
        int col = threadIdx.x;
        float s = s_sum[0][col] + s_sum[1][col] + s_sum[2][col] + s_sum[3][col];
        float q = s_sq[0][col]  + s_sq[1][col]  + s_sq[2][col]  + s_sq[3][col];
        int ps = (blockIdx.x & 63) * 64 + col;
        atomicAdd(&p_sum[ps], s);
        atomicAdd(&p_sq[ps], q);
    }
}

// ---- agg2: agg2h(fp16)[d] = (1+eps2)*h2[d] + sum h2[src]  (h2 fp8, 32 feats)
//      4 lanes x uint2 cover a 32B row; 16 edge streams
__global__ __launch_bounds__(256) void k_agg2(
    const unsigned int* __restrict__ h28, const int* __restrict__ off,
    const int* __restrict__ csr, const float* __restrict__ eps2p,
    __half* __restrict__ agg2h, int n)
{
    int node = blockIdx.x * 4 + (threadIdx.x >> 6);
    if (node >= n) return;
    int lane = threadIdx.x & 63;
    int c = lane & 3;      // uint2 column
    int g = lane >> 2;     // 0..15 edge streams
    int o = off[node], e = off[node + 1];
    const uint2* h282 = (const uint2*)h28;
    float4 aLo = {0,0,0,0}, aHi = {0,0,0,0};
    if (g == 0) {
        uint2 v = h282[(size_t)node * 4 + c];
        float4 lo = fp8x4_to_f4(v.x), hi = fp8x4_to_f4(v.y);
        float ep = 1.0f + eps2p[0];
        aLo.x = ep * lo.x; aLo.y = ep * lo.y; aLo.z = ep * lo.z; aLo.w = ep * lo.w;
        aHi.x = ep * hi.x; aHi.y = ep * hi.y; aHi.z = ep * hi.z; aHi.w = ep * hi.w;
    }
    int j = o + g;
    for (; j + 16 < e; j += 32) {
        int s0 = csr[j], s1 = csr[j + 16];
        uint2 w0 = h282[(size_t)s0 * 4 + c];
        uint2 w1 = h282[(size_t)s1 * 4 + c];
        add4(aLo, fp8x4_to_f4(w0.x)); add4(aHi, fp8x4_to_f4(w0.y));
        add4(aLo, fp8x4_to_f4(w1.x)); add4(aHi, fp8x4_to_f4(w1.y));
    }
    for (; j < e; j += 16) {
        uint2 w = h282[(size_t)csr[j] * 4 + c];
        add4(aLo, fp8x4_to_f4(w.x)); add4(aHi, fp8x4_to_f4(w.y));
    }
    #pragma unroll
    for (int d = 4; d < 64; d <<= 1) {
        aLo.x += __shfl_xor(aLo.x, d, 64); aLo.y += __shfl_xor(aLo.y, d, 64);
        aLo.z += __shfl_xor(aLo.z, d, 64); aLo.w += __shfl_xor(aLo.w, d, 64);
        aHi.x += __shfl_xor(aHi.x, d, 64); aHi.y += __shfl_xor(aHi.y, d, 64);
        aHi.z += __shfl_xor(aHi.z, d, 64); aHi.w += __shfl_xor(aHi.w, d, 64);
    }
    if (g == 0)
        ((usv8*)agg2h)[(size_t)node * 4 + c] = f4x2_to_h8(aLo, aHi);
}

// ---------------- fold BN into affine (reduces 64 partial slots) ----------
__global__ void k_bnfin(const float* __restrict__ p_sum, const float* __restrict__ p_sq,
                        const float* __restrict__ gamma, const float* __restrict__ beta,
                        float nf, float* __restrict__ a, float* __restrict__ c)
{
    int i = threadIdx.x;   // 64
    float s = 0.f, q = 0.f;
    for (int k = 0; k < 64; ++k) { s += p_sum[k*64 + i]; q += p_sq[k*64 + i]; }
    float mu  = s / nf;
    float var = q / nf - mu * mu;
    float av  = gamma[i] * rsqrtf(var + 1e-5f);
    a[i] = av;
    c[i] = beta[i] - av * mu;
}

// ---- mlp1b: h28(fp8) = relu(a1*h1+c1) @ w1b + b1b  (h1 fp16) ----
__global__ __launch_bounds__(256) void k_mlp1b(
    const __half* __restrict__ h1, const float* __restrict__ a1,
    const float* __restrict__ c1, const float* __restrict__ w1b,
    const float* __restrict__ b1b, unsigned int* __restrict__ h28, int n)
{
    __shared__ float  xs[128 * 65];
    __shared__ float4 ws[64 * 8];
    __shared__ float  as[64], cs[64];
    int tid = threadIdx.x;
    #pragma unroll
    for (int i = tid; i < 64 * 8; i += 256) ws[i] = ((const float4*)w1b)[i];
    if (tid < 64) { as[tid] = a1[tid]; cs[tid] = c1[tid]; }
    __syncthreads();
    int row0 = blockIdx.x * 128;
    for (int i = tid; i < 128 * 16; i += 256) {
        int r = i >> 4, k4 = i & 15;
        float4 v = {0.f, 0.f, 0.f, 0.f};
        if (row0 + r < n) {
            v = h4_to_f4(((const ushort4*)h1)[(size_t)(row0 + r) * 16 + k4]);
            v.x = fmaxf(as[k4*4+0] * v.x + cs[k4*4+0], 0.f);
            v.y = fmaxf(as[k4*4+1] * v.y + cs[k4*4+1], 0.f);
            v.z = fmaxf(as[k4*4+2] * v.z + cs[k4*4+2], 0.f);
            v.w = fmaxf(as[k4*4+3] * v.w + cs[k4*4+3], 0.f);
        }
        xs[r * 65 + k4 * 4 + 0] = v.x;
        xs[r * 65 + k4 * 4 + 1] = v.y;
        xs[r * 65 + k4 * 4 + 2] = v.z;
        xs[r * 65 + k4 * 4 + 3] = v.w;
    }
    __syncthreads();
    int c4 = tid & 7, rg = tid >> 3;
    float4 bv = ((const float4*)b1b)[c4];
    float4 acc[4] = {bv, bv, bv, bv};
    const float* xr = xs + rg * 4 * 65;
    #pragma unroll 8
    for (int k = 0; k < 64; ++k) {
        float4 wv = ws[k * 8 + c4];
        fma4(acc[0], xr[k +   0], wv);
        fma4(acc[1], xr[k +  65], wv);
        fma4(acc[2], xr[k + 130], wv);
        fma4(acc[3], xr[k + 195], wv);
    }
    #pragma unroll
    for (int i = 0; i < 4; ++i) {
        int row = row0 + rg * 4 + i;
        if (row < n) h28[(size_t)row * 8 + c4] = f4_to_fp8x4(acc[i]);
    }
}

// ---- gemm2: h3(fp16) = agg2h(fp16) @ w2a + b2a ; fused BN2 partial stats ----
__global__ __launch_bounds__(256) void k_gemm2(
    const __half* __restrict__ agg2h, const float* __restrict__ w2a,
    const float* __restrict__ b2a, __half* __restrict__ h3, int n,
    float* __restrict__ p_sum, float* __restrict__ p_sq)
{
    __shared__ float  xs[64 * 33];
    __shared__ float4 ws[32 * 16];
    __shared__ float  s_sum[64], s_sq[64];
    int tid = threadIdx.x;
    if (tid < 64) { s_sum[tid] = 0.f; s_sq[tid] = 0.f; }
    #pragma unroll
    for (int i = tid; i < 32 * 16; i += 256) ws[i] = ((const float4*)w2a)[i];
    int row0 = blockIdx.x * 64;
    for (int i = tid; i < 64 * 8; i += 256) {
        int r = i >> 3, k4 = i & 7;
        float4 v = {0.f, 0.f, 0.f, 0.f};
        if (row0 + r < n) v = h4_to_f4(((const ushort4*)agg2h)[(size_t)(row0 + r) * 8 + k4]);
        xs[r * 33 + k4 * 4 + 0] = v.x;
        xs[r * 33 + k4 * 4 + 1] = v.y;
        xs[r * 33 + k4 * 4 + 2] = v.z;
        xs[r * 33 + k4 * 4 + 3] = v.w;
    }
    __syncthreads();
    int c4 = tid & 15, rg = tid >> 4;
    float4 bv = ((const float4*)b2a)[c4];
    float4 acc[4] = {bv, bv, bv, bv};
    const float* xr = xs + rg * 4 * 33;
    #pragma unroll
    for (int k = 0; k < 32; ++k) {
        float4 wv = ws[k * 16 + c4];
        fma4(acc[0], xr[k +  0], wv);
        fma4(acc[1], xr[k + 33], wv);
        fma4(acc[2], xr[k + 66], wv);
        fma4(acc[3], xr[k + 99], wv);
    }
    float cs_[4] = {0,0,0,0}, cq_[4] = {0,0,0,0};
    #pragma unroll
    for (int i = 0; i < 4; ++i) {
        int row = row0 + rg * 4 + i;
        if (row < n) {
            ((ushort4*)h3)[(size_t)row * 16 + c4] = f4_to_h4(acc[i]);
            cs_[0] += acc[i].x; cq_[0] += acc[i].x * acc[i].x;
            cs_[1] += acc[i].y; cq_[1] += acc[i].y * acc[i].y;
            cs_[2] += acc[i].z; cq_[2] += acc[i].z * acc[i].z;
            cs_[3] += acc[i].w; cq_[3] += acc[i].w * acc[i].w;
        }
    }
    #pragma unroll
    for (int jj = 0; jj < 4; ++jj) {
        atomicAdd(&s_sum[c4 * 4 + jj], cs_[jj]);
        atomicAdd(&s_sq[c4 * 4 + jj],  cq_[jj]);
    }
    __syncthreads();
    if (tid < 64) {
        int ps = (blockIdx.x & 63) * 64 + tid;
        atomicAdd(&p_sum[ps], s_sum[tid]);
        atomicAdd(&p_sq[ps],  s_sq[tid]);
    }
}

// ---- final: h4 = relu(a2*h3+c2) @ w2b + b2b ; pool per graph (h3 fp16) ----
__global__ __launch_bounds__(256) void k_final(
    const __half* __restrict__ h3, const float* __restrict__ a2,
    const float* __restrict__ c2, const float* __restrict__ w2b,
    const float* __restrict__ b2b, const int* __restrict__ batch,
    float* __restrict__ pool, float* __restrict__ cnt, int n)
{
    __shared__ float  xs[64 * 65];
    __shared__ float4 ws[64 * 4];
    __shared__ float  as[64], cs[64];
    __shared__ float  pl[G_GRAPHS * 16];
    __shared__ float  cl[G_GRAPHS];
    int tid = threadIdx.x;
    for (int i = tid; i < 256; i += 256) ws[i] = ((const float4*)w2b)[i];
    if (tid < 64) { as[tid] = a2[tid]; cs[tid] = c2[tid]; cl[tid] = 0.f; }
    for (int i = tid; i < G_GRAPHS * 16; i += 256) pl[i] = 0.f;
    __syncthreads();
    int row0 = blockIdx.x * 64;
    for (int i = tid; i < 64 * 16; i += 256) {
        int r = i >> 4, k4 = i & 15;
        float4 v = {0.f, 0.f, 0.f, 0.f};
        if (row0 + r < n) {
            v = h4_to_f4(((const ushort4*)h3)[(size_t)(row0 + r) * 16 + k4]);
            v.x = fmaxf(as[k4*4+0] * v.x + cs[k4*4+0], 0.f);
            v.y = fmaxf(as[k4*4+1] * v.y + cs[k4*4+1], 0.f);
            v.z = fmaxf(as[k4*4+2] * v.z + cs[k4*4+2], 0.f);
            v.w = fmaxf(as[k4*4+3] * v.w + cs[k4*4+3], 0.f);
        }
        xs[r * 65 + k4 * 4 + 0] = v.x;
        xs[r * 65 + k4 * 4 + 1] = v.y;
        xs[r * 65 + k4 * 4 + 2] = v.z;
        xs[r * 65 + k4 * 4 + 3] = v.w;
    }
    __syncthreads();
    int c4 = tid & 3, r = tid >> 2;
    float4 acc = ((const float4*)b2b)[c4];
    const float* xr = xs + r * 65;
    #pragma unroll 8
    for (int k = 0; k < 64; ++k) {
        float4 wv = ws[k * 4 + c4];
        fma4(acc, xr[k], wv);
    }
    int row = row0 + r;
    if (row < n) {
        int g = batch[row];
        if (c4 == 0) atomicAdd(&cl[g], 1.f);
        float* pp = &pl[g * 16 + c4 * 4];
        atomicAdd(pp + 0, acc.x); atomicAdd(pp + 1, acc.y);
        atomicAdd(pp + 2, acc.z); atomicAdd(pp + 3, acc.w);
    }
    __syncthreads();
    if (tid < 64 && cl[tid] != 0.f) atomicAdd(&cnt[tid], cl[tid]);
    for (int i = tid; i < G_GRAPHS * 16; i += 256) {
        int g = i >> 4;
        if (cl[g] != 0.f) atomicAdd(&pool[i], pl[i]);
    }
}

// ---------------- head ----------------
__global__ void k_head(const float* __restrict__ pool, const float* __restrict__ cnt,
                       const float* __restrict__ lw, const float* __restrict__ lb,
                       float* __restrict__ out)
{
    int g = threadIdx.x;
    float cv = fmaxf(cnt[g], 1.0f);
    float acc = lb[0];
    #pragma unroll
    for (int f = 0; f < 16; ++f) acc += (pool[g * 16 + f] / cv) * lw[f];
    out[g] = 1.0f / (1.0f + expf(-acc));
}

extern "C" void kernel_launch(void* const* d_in, const int* in_sizes, int n_in,
                              void* d_out, int out_size, void* d_ws, size_t ws_size,
                              hipStream_t stream)
{
    const float* x    = (const float*)d_in[0];
    const int*   eidx = (const int*)d_in[1];
    const int*   batch= (const int*)d_in[2];
    const float* eps1 = (const float*)d_in[3];
    const float* eps2 = (const float*)d_in[4];
    const float* w1a  = (const float*)d_in[5];
    const float* b1a  = (const float*)d_in[6];
    const float* g1   = (const float*)d_in[7];
    const float* bt1  = (const float*)d_in[8];
    const float* w1b  = (const float*)d_in[9];
    const float* b1b  = (const float*)d_in[10];
    const float* w2a  = (const float*)d_in[11];
    const float* b2a  = (const float*)d_in[12];
    const float* g2   = (const float*)d_in[13];
    const float* bt2  = (const float*)d_in[14];
    const float* w2b  = (const float*)d_in[15];
    const float* b2b  = (const float*)d_in[16];
    const float* lw   = (const float*)d_in[17];
    const float* lb   = (const float*)d_in[18];
    float* out = (float*)d_out;

    int n  = in_sizes[0] / 128;
    int nE = in_sizes[1] / 2;
    const int* srcI = eidx;
    const int* dstI = eidx + nE;
    int vec4ok = ((nE & 3) == 0) && ((((uintptr_t)eidx) & 15) == 0);

    char* wsb = (char*)d_ws;
    size_t nn = (size_t)n;
    unsigned int* y8  = (unsigned int*)wsb;             // n*64 fp8
    __half* h1        = (__half*)(wsb + nn * 64);       // n*64 fp16 (reused as h3)
    unsigned int* h28 = (unsigned int*)(wsb + nn * 192);// n*32 fp8
    __half* agg2h     = (__half*)(wsb + nn * 224);      // n*32 fp16
    __half* h3        = h1;                              // alias (h1 dead after mlp1b)
    float* stats = (float*)(wsb + nn * 288);
    float* a1     = stats;          float* c1     = stats + 64;
    float* a2     = stats + 128;    float* c2     = stats + 192;
    float* pool   = stats + 256;    float* cntb   = stats + 1280;
    float* p_sum1 = stats + 1344;   float* p_sq1  = stats + 5440;
    float* p_sum2 = stats + 9536;   float* p_sq2  = stats + 13632;
    // stats region total: 17728 floats

    int cblocks = (nE + C_CHUNK - 1) / C_CHUNK;   // must be <= 256
    int nbins   = (n + BIN_SIZE - 1) >> BIN_SHIFT;

    int* off     = (int*)(stats + 17728);       // n+1
    int* csr     = off + (n + 1);               // nE
    int* binCnt  = csr + nE;                    // NBINS_CAP+1
    int* binOff  = binCnt + NBINS_CAP + 1;      // NBINS_CAP+1
    int* staging = binOff + NBINS_CAP + 1;      // nE
    int* hist    = staging + nE;                // cblocks * nbins

    hipMemsetAsync(stats + 256, 0, (17728 - 256) * sizeof(float), stream);

    int tiles64  = (n + 63) / 64;
    int tiles128 = (n + 127) / 128;
    int nblocks4 = (n + 3) / 4;

    k_g1A<<<tiles64 + cblocks, 256, 0, stream>>>(x, w1a, y8, n, tiles64,
                                                 dstI, hist, nE, nbins, vec4ok);
    k_binB1<<<nbins, 256, 0, stream>>>(hist, cblocks, nbins, binCnt);
    k_binB2<<<1, 1024, 0, stream>>>(binCnt, nbins, nE, binOff, off, n);
    k_binC2<<<cblocks, 256, 0, stream>>>(srcI, dstI, binOff, hist, staging, nE, nbins, vec4ok);
    k_binD<<<nbins, 256, 0, stream>>>(binOff, staging, off, csr, n);

    k_agg1<<<nblocks4, 256, 0, stream>>>(y8, off, csr, b1a, eps1, h1, n, p_sum1, p_sq1);
    k_bnfin<<<1, 64, 0, stream>>>(p_sum1, p_sq1, g1, bt1, (float)n, a1, c1);
    k_mlp1b<<<tiles128, 256, 0, stream>>>(h1, a1, c1, w1b, b1b, h28, n);
    k_agg2<<<nblocks4, 256, 0, stream>>>(h28, off, csr, eps2, agg2h, n);
    k_gemm2<<<tiles64, 256, 0, stream>>>(agg2h, w2a, b2a, h3, n, p_sum2, p_sq2);
    k_bnfin<<<1, 64, 0, stream>>>(p_sum2, p_sq2, g2, bt2, (float)n, a2, c2);
    k_final<<<tiles64, 256, 0, stream>>>(h3, a2, c2, w2b, b2b, batch, pool, cntb, n);
    k_head<<<1, 64, 0, stream>>>(pool, cntb, lw, lb, out);
}

// Round 16
// 277.726 us; speedup vs baseline: 1.1804x; 1.1075x over previous
//
#include <hip/hip_runtime.h>
#include <hip/hip_fp16.h>
#include <math.h>

#define G_GRAPHS 64
#define BIN_SHIFT 7
#define BIN_SIZE 128
#define NBINS_CAP 1024      // supports n <= 131072 (and src fits 17 bits)
#define C_CHUNK 16384       // cblocks must be <= 256 (nE <= 4.19M)

typedef unsigned short usv8 __attribute__((ext_vector_type(8)));

__device__ __forceinline__ void fma4(float4& a, float s, float4 w) {
    a.x += s * w.x; a.y += s * w.y; a.z += s * w.z; a.w += s * w.w;
}
__device__ __forceinline__ void add4(float4& a, float4 b) {
    a.x += b.x; a.y += b.y; a.z += b.z; a.w += b.w;
}
__device__ __forceinline__ float4 h4_to_f4(ushort4 u) {
    return make_float4(__half2float(__ushort_as_half(u.x)),
                       __half2float(__ushort_as_half(u.y)),
                       __half2float(__ushort_as_half(u.z)),
                       __half2float(__ushort_as_half(u.w)));
}
__device__ __forceinline__ ushort4 f4_to_h4(float4 f) {
    ushort4 u;
    u.x = __half_as_ushort(__float2half_rn(f.x));
    u.y = __half_as_ushort(__float2half_rn(f.y));
    u.z = __half_as_ushort(__float2half_rn(f.z));
    u.w = __half_as_ushort(__float2half_rn(f.w));
    return u;
}
__device__ __forceinline__ usv8 f4x2_to_h8(float4 a, float4 b) {
    usv8 r;
    r.s0 = __half_as_ushort(__float2half_rn(a.x));
    r.s1 = __half_as_ushort(__float2half_rn(a.y));
    r.s2 = __half_as_ushort(__float2half_rn(a.z));
    r.s3 = __half_as_ushort(__float2half_rn(a.w));
    r.s4 = __half_as_ushort(__float2half_rn(b.x));
    r.s5 = __half_as_ushort(__float2half_rn(b.y));
    r.s6 = __half_as_ushort(__float2half_rn(b.z));
    r.s7 = __half_as_ushort(__float2half_rn(b.w));
    return r;
}

// ---------------- fp8 e4m3 (OCP) pack/unpack ----------------
__device__ __forceinline__ float4 fp8x4_to_f4(unsigned int w) {
#if __has_builtin(__builtin_amdgcn_cvt_f32_fp8)
    float4 r;
    r.x = __builtin_amdgcn_cvt_f32_fp8((int)w, 0);
    r.y = __builtin_amdgcn_cvt_f32_fp8((int)w, 1);
    r.z = __builtin_amdgcn_cvt_f32_fp8((int)w, 2);
    r.w = __builtin_amdgcn_cvt_f32_fp8((int)w, 3);
    return r;
#else
    const float sc = 1.329227995784916e+36f;   // 2^120
    unsigned b0 = w & 0xffu, b1 = (w >> 8) & 0xffu,
             b2 = (w >> 16) & 0xffu, b3 = (w >> 24) & 0xffu;
    float4 r;
    r.x = __uint_as_float(((b0 & 0x80u) << 24) | ((b0 & 0x7fu) << 20)) * sc;
    r.y = __uint_as_float(((b1 & 0x80u) << 24) | ((b1 & 0x7fu) << 20)) * sc;
    r.z = __uint_as_float(((b2 & 0x80u) << 24) | ((b2 & 0x7fu) << 20)) * sc;
    r.w = __uint_as_float(((b3 & 0x80u) << 24) | ((b3 & 0x7fu) << 20)) * sc;
    return r;
#endif
}
__device__ __forceinline__ unsigned int f4_to_fp8x4(float4 f) {
#if __has_builtin(__builtin_amdgcn_cvt_pk_fp8_f32)
    int v = __builtin_amdgcn_cvt_pk_fp8_f32(f.x, f.y, 0, false);
    v = __builtin_amdgcn_cvt_pk_fp8_f32(f.z, f.w, v, true);
    return (unsigned int)v;
#else
    const float sc = 7.52316384526264e-37f;    // 2^-120
    float vv[4] = {f.x, f.y, f.z, f.w};
    unsigned out = 0;
    #pragma unroll
    for (int i = 0; i < 4; ++i) {
        unsigned u = __float_as_uint(vv[i] * sc);
        unsigned s = (u >> 24) & 0x80u;
        u += 0x00080000u;
        unsigned m = (u >> 20) & 0x7fu;
        out |= (s | m) << (8 * i);
    }
    return out;
#endif
}

// ---- g1A: fused gemm1 (blocks < tiles64) and binA (blocks >= tiles64) ----
__global__ __launch_bounds__(256) void k_g1A(
    const float* __restrict__ x, const float* __restrict__ w1a,
    unsigned int* __restrict__ y8, int n, int tiles64,
    const int* __restrict__ dst, int* __restrict__ hist, int nE, int nbins,
    int vec4ok)
{
    __shared__ float  xs[64 * 129];
    __shared__ float4 ws[128 * 16];
    __shared__ int    cnt[NBINS_CAP];
    int tid = threadIdx.x;
    if (blockIdx.x < tiles64) {
        // ---------- gemm1 ----------
        const float4* w4 = (const float4*)w1a;
        #pragma unroll
        for (int i = tid; i < 128 * 16; i += 256) ws[i] = w4[i];
        int row0 = blockIdx.x * 64;
        for (int i = tid; i < 64 * 32; i += 256) {
            int r = i >> 5, k4 = i & 31;
            float4 v = {0.f, 0.f, 0.f, 0.f};
            if (row0 + r < n) v = ((const float4*)x)[(size_t)(row0 + r) * 32 + k4];
            xs[r * 129 + k4 * 4 + 0] = v.x;
            xs[r * 129 + k4 * 4 + 1] = v.y;
            xs[r * 129 + k4 * 4 + 2] = v.z;
            xs[r * 129 + k4 * 4 + 3] = v.w;
        }
        __syncthreads();
        int c4 = tid & 15, rg = tid >> 4;
        float4 acc[4] = {{0,0,0,0},{0,0,0,0},{0,0,0,0},{0,0,0,0}};
        const float* xr = xs + rg * 4 * 129;
        #pragma unroll 8
        for (int k = 0; k < 128; ++k) {
            float4 wv = ws[k * 16 + c4];
            fma4(acc[0], xr[k +   0], wv);
            fma4(acc[1], xr[k + 129], wv);
            fma4(acc[2], xr[k + 258], wv);
            fma4(acc[3], xr[k + 387], wv);
        }
        #pragma unroll
        for (int i = 0; i < 4; ++i) {
            int row = row0 + rg * 4 + i;
            if (row < n) y8[(size_t)row * 16 + c4] = f4_to_fp8x4(acc[i]);
        }
    } else {
        // ---------- binA ----------
        int blk = blockIdx.x - tiles64;
        for (int i = tid; i < nbins; i += 256) cnt[i] = 0;
        __syncthreads();
        int base = blk * C_CHUNK;
        int end  = min(base + C_CHUNK, nE);
        int done = base;
        if (vec4ok) {
            int cnt4 = (end - base) >> 2;
            const int4* d4 = (const int4*)(dst + base);
            for (int i = tid; i < cnt4; i += 256) {
                int4 v = d4[i];
                atomicAdd(&cnt[v.x >> BIN_SHIFT], 1);
                atomicAdd(&cnt[v.y >> BIN_SHIFT], 1);
                atomicAdd(&cnt[v.z >> BIN_SHIFT], 1);
                atomicAdd(&cnt[v.w >> BIN_SHIFT], 1);
            }
            done = base + (cnt4 << 2);
        }
        for (int e = done + tid; e < end; e += 256)
            atomicAdd(&cnt[dst[e] >> BIN_SHIFT], 1);
        __syncthreads();
        int* hrow = hist + (size_t)blk * nbins;
        for (int i = tid; i < nbins; i += 256) hrow[i] = cnt[i];
    }
}

// ---- binB1: per bin, exclusive-scan hist column across blocks; binCnt = total
__global__ __launch_bounds__(256) void k_binB1(
    int* __restrict__ hist, int cblocks, int nbins, int* __restrict__ binCnt)
{
    __shared__ int sb[256];
    int b = blockIdx.x;
    int t = threadIdx.x;
    int v = (t < cblocks) ? hist[(size_t)t * nbins + b] : 0;
    sb[t] = v;
    __syncthreads();
    for (int d = 1; d < 256; d <<= 1) {
        int tt = (t >= d) ? sb[t - d] : 0;
        __syncthreads();
        sb[t] += tt;
        __syncthreads();
    }
    if (t < cblocks) hist[(size_t)t * nbins + b] = sb[t] - v;   // exclusive
    if (t == 0) binCnt[b] = sb[255];
}

// ---- binB2: scan binCnt -> binOff; off[n]=nE ----
__global__ __launch_bounds__(1024) void k_binB2(
    const int* __restrict__ binCnt, int nbins, int nE,
    int* __restrict__ binOff, int* __restrict__ off, int n)
{
    __shared__ int sb[1024];
    int tid = threadIdx.x;
    int v = (tid < nbins) ? binCnt[tid] : 0;
    sb[tid] = v;
    __syncthreads();
    for (int d = 1; d < 1024; d <<= 1) {
        int t = (tid >= d) ? sb[tid - d] : 0;
        __syncthreads();
        sb[tid] += t;
        __syncthreads();
    }
    if (tid < nbins) binOff[tid] = sb[tid] - v;
    if (tid == 0) { binOff[nbins] = nE; off[n] = nE; }
}

// ---- binC2: single pass — load per-block bases, scatter with LDS cursor ----
__global__ __launch_bounds__(256) void k_binC2(
    const int* __restrict__ src, const int* __restrict__ dst,
    const int* __restrict__ binOff, const int* __restrict__ hist,
    int* __restrict__ staging, int nE, int nbins, int vec4ok)
{
    __shared__ int cnt[NBINS_CAP];
    const int* hrow = hist + (size_t)blockIdx.x * nbins;
    for (int i = threadIdx.x; i < nbins; i += 256)
        cnt[i] = binOff[i] + hrow[i];
    __syncthreads();
    int base = blockIdx.x * C_CHUNK;
    int end  = min(base + C_CHUNK, nE);
    int done = base;
    if (vec4ok) {
        int cnt4 = (end - base) >> 2;
        const int4* d4 = (const int4*)(dst + base);
        const int4* s4 = (const int4*)(src + base);
        for (int i = threadIdx.x; i < cnt4; i += 256) {
            int4 dv = d4[i]; int4 sv = s4[i];
            int b, p;
            b = dv.x >> BIN_SHIFT; p = atomicAdd(&cnt[b], 1);
            staging[p] = ((dv.x & (BIN_SIZE-1)) << 17) | sv.x;
            b = dv.y >> BIN_SHIFT; p = atomicAdd(&cnt[b], 1);
            staging[p] = ((dv.y & (BIN_SIZE-1)) << 17) | sv.y;
            b = dv.z >> BIN_SHIFT; p = atomicAdd(&cnt[b], 1);
            staging[p] = ((dv.z & (BIN_SIZE-1)) << 17) | sv.z;
            b = dv.w >> BIN_SHIFT; p = atomicAdd(&cnt[b], 1);
            staging[p] = ((dv.w & (BIN_SIZE-1)) << 17) | sv.w;
        }
        done = base + (cnt4 << 2);
    }
    for (int e = done + threadIdx.x; e < end; e += 256) {
        int d = dst[e], s = src[e];
        int b = d >> BIN_SHIFT;
        int p = atomicAdd(&cnt[b], 1);
        staging[p] = ((d & (BIN_SIZE - 1)) << 17) | s;
    }
}

__global__ __launch_bounds__(256) void k_binD(
    const int* __restrict__ binOff, const int* __restrict__ staging,
    int* __restrict__ off, int* __restrict__ csr, int n)
{
    __shared__ int deg[BIN_SIZE];
    __shared__ int cur[BIN_SIZE];
    int b = blockIdx.x;
    int s = binOff[b], e = binOff[b + 1];
    int tid = threadIdx.x;
    if (tid < BIN_SIZE) deg[tid] = 0;
    __syncthreads();
    for (int j = s + tid; j < e; j += 256)
        atomicAdd(&deg[staging[j] >> 17], 1);
    __syncthreads();
    if (tid < BIN_SIZE) cur[tid] = deg[tid];
    __syncthreads();
    for (int d = 1; d < BIN_SIZE; d <<= 1) {
        int t = (tid >= d && tid < BIN_SIZE) ? cur[tid - d] : 0;
        __syncthreads();
        if (tid < BIN_SIZE) cur[tid] += t;
        __syncthreads();
    }
    if (tid < BIN_SIZE) {
        int node = b * BIN_SIZE + tid;
        int ex = s + cur[tid] - deg[tid];
        if (node < n) off[node] = ex;
        cur[tid] = ex;
    }
    __syncthreads();
    for (int j = s + tid; j < e; j += 256) {
        int pk = staging[j];
        int p = atomicAdd(&cur[pk >> 17], 1);
        csr[p] = pk & 0x1FFFF;
    }
}

// ---- agg1: h1(fp16)[d] = (1+eps1)*y[d] + b1a + sum_{src} y[src]  (y fp8)
//      8 lanes x uint2 (8B) cover a 64B row; 8 edge streams x 2-deep
__global__ __launch_bounds__(256) void k_agg1(
    const unsigned int* __restrict__ y8, const int* __restrict__ off,
    const int* __restrict__ csr, const float* __restrict__ b1a,
    const float* __restrict__ eps1p, __half* __restrict__ h1, int n,
    float* __restrict__ p_sum, float* __restrict__ p_sq)
{
    __shared__ float s_sum[4][64];
    __shared__ float s_sq[4][64];
    int slot = threadIdx.x >> 6;
    int lane = threadIdx.x & 63;
    int node = blockIdx.x * 4 + slot;
    int c = lane & 7;      // uint2 column (8 bytes each)
    int g = lane >> 3;     // 0..7 edge streams
    bool valid = node < n;
    int o = 0, e = 0;
    if (valid) { o = off[node]; e = off[node + 1]; }
    const uint2* y82 = (const uint2*)y8;
    float4 aLo = {0,0,0,0}, aHi = {0,0,0,0};
    if (valid && g == 0) {
        uint2 v = y82[(size_t)node * 8 + c];
        float4 lo = fp8x4_to_f4(v.x), hi = fp8x4_to_f4(v.y);
        float4 b0 = ((const float4*)b1a)[c * 2];
        float4 b1 = ((const float4*)b1a)[c * 2 + 1];
        float ep = 1.0f + eps1p[0];
        aLo.x = ep * lo.x + b0.x; aLo.y = ep * lo.y + b0.y;
        aLo.z = ep * lo.z + b0.z; aLo.w = ep * lo.w + b0.w;
        aHi.x = ep * hi.x + b1.x; aHi.y = ep * hi.y + b1.y;
        aHi.z = ep * hi.z + b1.z; aHi.w = ep * hi.w + b1.w;
    }
    int j = o + g;
    for (; j + 8 < e; j += 16) {
        int s0 = csr[j], s1 = csr[j + 8];
        uint2 w0 = y82[(size_t)s0 * 8 + c];
        uint2 w1 = y82[(size_t)s1 * 8 + c];
        add4(aLo, fp8x4_to_f4(w0.x)); add4(aHi, fp8x4_to_f4(w0.y));
        add4(aLo, fp8x4_to_f4(w1.x)); add4(aHi, fp8x4_to_f4(w1.y));
    }
    for (; j < e; j += 8) {
        uint2 w = y82[(size_t)csr[j] * 8 + c];
        add4(aLo, fp8x4_to_f4(w.x)); add4(aHi, fp8x4_to_f4(w.y));
    }
    // reduce across 8 streams (xor 8,16,32)
    #pragma unroll
    for (int d = 8; d < 64; d <<= 1) {
        aLo.x += __shfl_xor(aLo.x, d, 64); aLo.y += __shfl_xor(aLo.y, d, 64);
        aLo.z += __shfl_xor(aLo.z, d, 64); aLo.w += __shfl_xor(aLo.w, d, 64);
        aHi.x += __shfl_xor(aHi.x, d, 64); aHi.y += __shfl_xor(aHi.y, d, 64);
        aHi.z += __shfl_xor(aHi.z, d, 64); aHi.w += __shfl_xor(aHi.w, d, 64);
    }
    if (g == 0) {
        if (valid) ((usv8*)h1)[(size_t)node * 8 + c] = f4x2_to_h8(aLo, aHi);
        float v0 = valid ? aLo.x : 0.f, v1 = valid ? aLo.y : 0.f;
        float v2 = valid ? aLo.z : 0.f, v3 = valid ? aLo.w : 0.f;
        float v4 = valid ? aHi.x : 0.f, v5 = valid ? aHi.y : 0.f;
        float v6 = valid ? aHi.z : 0.f, v7 = valid ? aHi.w : 0.f;
        s_sum[slot][8*c+0] = v0; s_sum[slot][8*c+1] = v1;
        s_sum[slot][8*c+2] = v2; s_sum[slot][8*c+3] = v3;
        s_sum[slot][8*c+4] = v4; s_sum[slot][8*c+5] = v5;
        s_sum[slot][8*c+6] = v6; s_sum[slot][8*c+7] = v7;
        s_sq[slot][8*c+0] = v0*v0; s_sq[slot][8*c+1] = v1*v1;
        s_sq[slot][8*c+2] = v2*v2; s_sq[slot][8*c+3] = v3*v3;
        s_sq[slot][8*c+4] = v4*v4; s_sq[slot][8*c+5] = v5*v5;
        s_sq[slot][8*c+6] = v6*v6; s_sq[slot][8*c+7] = v7*v7;
    }
    __syncthreads();
    if (threadIdx.x < 64) {
        int col = threadIdx.x;
        float s = s_sum[0][col] + s_sum[1][col] + s_sum[2][col] + s_sum[3][col];
        float q = s_sq[0][col]  + s_sq[1][col]  + s_sq[2][col]  + s_sq[3][col];
        int ps = (blockIdx.x & 63) * 64 + col;
        atomicAdd(&p_sum[ps], s);
        atomicAdd(&p_sq[ps], q);
    }
}

// ---- agg2: agg2h(fp16)[d] = (1+eps2)*h2[d] + sum h2[src]  (h2 fp8, 32 feats)
//      4 lanes x uint2 cover a 32B row; 16 edge streams
__global__ __launch_bounds__(256) void k_agg2(
    const unsigned int* __restrict__ h28, const int* __restrict__ off,
    const int* __restrict__ csr, const float* __restrict__ eps2p,
    __half* __restrict__ agg2h, int n)
{
    int node = blockIdx.x * 4 + (threadIdx.x >> 6);
    if (node >= n) return;
    int lane = threadIdx.x & 63;
    int c = lane & 3;      // uint2 column
    int g = lane >> 2;     // 0..15 edge streams
    int o = off[node], e = off[node + 1];
    const uint2* h282 = (const uint2*)h28;
    float4 aLo = {0,0,0,0}, aHi = {0,0,0,0};
    if (g == 0) {
        uint2 v = h282[(size_t)node * 4 + c];
        float4 lo = fp8x4_to_f4(v.x), hi = fp8x4_to_f4(v.y);
        float ep = 1.0f + eps2p[0];
        aLo.x = ep * lo.x; aLo.y = ep * lo.y; aLo.z = ep * lo.z; aLo.w = ep * lo.w;
        aHi.x = ep * hi.x; aHi.y = ep * hi.y; aHi.z = ep * hi.z; aHi.w = ep * hi.w;
    }
    int j = o + g;
    for (; j + 16 < e; j += 32) {
        int s0 = csr[j], s1 = csr[j + 16];
        uint2 w0 = h282[(size_t)s0 * 4 + c];
        uint2 w1 = h282[(size_t)s1 * 4 + c];
        add4(aLo, fp8x4_to_f4(w0.x)); add4(aHi, fp8x4_to_f4(w0.y));
        add4(aLo, fp8x4_to_f4(w1.x)); add4(aHi, fp8x4_to_f4(w1.y));
    }
    for (; j < e; j += 16) {
        uint2 w = h282[(size_t)csr[j] * 4 + c];
        add4(aLo, fp8x4_to_f4(w.x)); add4(aHi, fp8x4_to_f4(w.y));
    }
    #pragma unroll
    for (int d = 4; d < 64; d <<= 1) {
        aLo.x += __shfl_xor(aLo.x, d, 64); aLo.y += __shfl_xor(aLo.y, d, 64);
        aLo.z += __shfl_xor(aLo.z, d, 64); aLo.w += __shfl_xor(aLo.w, d, 64);
        aHi.x += __shfl_xor(aHi.x, d, 64); aHi.y += __shfl_xor(aHi.y, d, 64);
        aHi.z += __shfl_xor(aHi.z, d, 64); aHi.w += __shfl_xor(aHi.w, d, 64);
    }
    if (g == 0)
        ((usv8*)agg2h)[(size_t)node * 4 + c] = f4x2_to_h8(aLo, aHi);
}

// ---------------- fold BN into affine (reduces 64 partial slots) ----------
__global__ void k_bnfin(const float* __restrict__ p_sum, const float* __restrict__ p_sq,
                        const float* __restrict__ gamma, const float* __restrict__ beta,
                        float nf, float* __restrict__ a, float* __restrict__ c)
{
    int i = threadIdx.x;   // 64
    float s = 0.f, q = 0.f;
    for (int k = 0; k < 64; ++k) { s += p_sum[k*64 + i]; q += p_sq[k*64 + i]; }
    float mu  = s / nf;
    float var = q / nf - mu * mu;
    float av  = gamma[i] * rsqrtf(var + 1e-5f);
    a[i] = av;
    c[i] = beta[i] - av * mu;
}

// ---- mlp1b: h28(fp8) = relu(a1*h1+c1) @ w1b + b1b  (h1 fp16) ----
__global__ __launch_bounds__(256) void k_mlp1b(
    const __half* __restrict__ h1, const float* __restrict__ a1,
    const float* __restrict__ c1, const float* __restrict__ w1b,
    const float* __restrict__ b1b, unsigned int* __restrict__ h28, int n)
{
    __shared__ float  xs[128 * 65];
    __shared__ float4 ws[64 * 8];
    __shared__ float  as[64], cs[64];
    int tid = threadIdx.x;
    #pragma unroll
    for (int i = tid; i < 64 * 8; i += 256) ws[i] = ((const float4*)w1b)[i];
    if (tid < 64) { as[tid] = a1[tid]; cs[tid] = c1[tid]; }
    __syncthreads();
    int row0 = blockIdx.x * 128;
    for (int i = tid; i < 128 * 16; i += 256) {
        int r = i >> 4, k4 = i & 15;
        float4 v = {0.f, 0.f, 0.f, 0.f};
        if (row0 + r < n) {
            v = h4_to_f4(((const ushort4*)h1)[(size_t)(row0 + r) * 16 + k4]);
            v.x = fmaxf(as[k4*4+0] * v.x + cs[k4*4+0], 0.f);
            v.y = fmaxf(as[k4*4+1] * v.y + cs[k4*4+1], 0.f);
            v.z = fmaxf(as[k4*4+2] * v.z + cs[k4*4+2], 0.f);
            v.w = fmaxf(as[k4*4+3] * v.w + cs[k4*4+3], 0.f);
        }
        xs[r * 65 + k4 * 4 + 0] = v.x;
        xs[r * 65 + k4 * 4 + 1] = v.y;
        xs[r * 65 + k4 * 4 + 2] = v.z;
        xs[r * 65 + k4 * 4 + 3] = v.w;
    }
    __syncthreads();
    int c4 = tid & 7, rg = tid >> 3;
    float4 bv = ((const float4*)b1b)[c4];
    float4 acc[4] = {bv, bv, bv, bv};
    const float* xr = xs + rg * 4 * 65;
    #pragma unroll 8
    for (int k = 0; k < 64; ++k) {
        float4 wv = ws[k * 8 + c4];
        fma4(acc[0], xr[k +   0], wv);
        fma4(acc[1], xr[k +  65], wv);
        fma4(acc[2], xr[k + 130], wv);
        fma4(acc[3], xr[k + 195], wv);
    }
    #pragma unroll
    for (int i = 0; i < 4; ++i) {
        int row = row0 + rg * 4 + i;
        if (row < n) h28[(size_t)row * 8 + c4] = f4_to_fp8x4(acc[i]);
    }
}

// ---- gemm2: h3(fp16) = agg2h(fp16) @ w2a + b2a ; fused BN2 partial stats ----
__global__ __launch_bounds__(256) void k_gemm2(
    const __half* __restrict__ agg2h, const float* __restrict__ w2a,
    const float* __restrict__ b2a, __half* __restrict__ h3, int n,
    float* __restrict__ p_sum, float* __restrict__ p_sq)
{
    __shared__ float  xs[64 * 33];
    __shared__ float4 ws[32 * 16];
    __shared__ float  s_sum[64], s_sq[64];
    int tid = threadIdx.x;
    if (tid < 64) { s_sum[tid] = 0.f; s_sq[tid] = 0.f; }
    #pragma unroll
    for (int i = tid; i < 32 * 16; i += 256) ws[i] = ((const float4*)w2a)[i];
    int row0 = blockIdx.x * 64;
    for (int i = tid; i < 64 * 8; i += 256) {
        int r = i >> 3, k4 = i & 7;
        float4 v = {0.f, 0.f, 0.f, 0.f};
        if (row0 + r < n) v = h4_to_f4(((const ushort4*)agg2h)[(size_t)(row0 + r) * 8 + k4]);
        xs[r * 33 + k4 * 4 + 0] = v.x;
        xs[r * 33 + k4 * 4 + 1] = v.y;
        xs[r * 33 + k4 * 4 + 2] = v.z;
        xs[r * 33 + k4 * 4 + 3] = v.w;
    }
    __syncthreads();
    int c4 = tid & 15, rg = tid >> 4;
    float4 bv = ((const float4*)b2a)[c4];
    float4 acc[4] = {bv, bv, bv, bv};
    const float* xr = xs + rg * 4 * 33;
    #pragma unroll
    for (int k = 0; k < 32; ++k) {
        float4 wv = ws[k * 16 + c4];
        fma4(acc[0], xr[k +  0], wv);
        fma4(acc[1], xr[k + 33], wv);
        fma4(acc[2], xr[k + 66], wv);
        fma4(acc[3], xr[k + 99], wv);
    }
    float cs_[4] = {0,0,0,0}, cq_[4] = {0,0,0,0};
    #pragma unroll
    for (int i = 0; i < 4; ++i) {
        int row = row0 + rg * 4 + i;
        if (row < n) {
            ((ushort4*)h3)[(size_t)row * 16 + c4] = f4_to_h4(acc[i]);
            cs_[0] += acc[i].x; cq_[0] += acc[i].x * acc[i].x;
            cs_[1] += acc[i].y; cq_[1] += acc[i].y * acc[i].y;
            cs_[2] += acc[i].z; cq_[2] += acc[i].z * acc[i].z;
            cs_[3] += acc[i].w; cq_[3] += acc[i].w * acc[i].w;
        }
    }
    #pragma unroll
    for (int jj = 0; jj < 4; ++jj) {
        atomicAdd(&s_sum[c4 * 4 + jj], cs_[jj]);
        atomicAdd(&s_sq[c4 * 4 + jj],  cq_[jj]);
    }
    __syncthreads();
    if (tid < 64) {
        int ps = (blockIdx.x & 63) * 64 + tid;
        atomicAdd(&p_sum[ps], s_sum[tid]);
        atomicAdd(&p_sq[ps],  s_sq[tid]);
    }
}

// ---- final: h4 = relu(a2*h3+c2) @ w2b + b2b ; pool per graph (h3 fp16) ----
__global__ __launch_bounds__(256) void k_final(
    const __half* __restrict__ h3, const float* __restrict__ a2,
    const float* __restrict__ c2, const float* __restrict__ w2b,
    const float* __restrict__ b2b, const int* __restrict__ batch,
    float* __restrict__ pool, float* __restrict__ cnt, int n)
{
    __shared__ float  xs[64 * 65];
    __shared__ float4 ws[64 * 4];
    __shared__ float  as[64], cs[64];
    __shared__ float  pl[G_GRAPHS * 16];
    __shared__ float  cl[G_GRAPHS];
    int tid = threadIdx.x;
    for (int i = tid; i < 256; i += 256) ws[i] = ((const float4*)w2b)[i];
    if (tid < 64) { as[tid] = a2[tid]; cs[tid] = c2[tid]; cl[tid] = 0.f; }
    for (int i = tid; i < G_GRAPHS * 16; i += 256) pl[i] = 0.f;
    __syncthreads();
    int row0 = blockIdx.x * 64;
    for (int i = tid; i < 64 * 16; i += 256) {
        int r = i >> 4, k4 = i & 15;
        float4 v = {0.f, 0.f, 0.f, 0.f};
        if (row0 + r < n) {
            v = h4_to_f4(((const ushort4*)h3)[(size_t)(row0 + r) * 16 + k4]);
            v.x = fmaxf(as[k4*4+0] * v.x + cs[k4*4+0], 0.f);
            v.y = fmaxf(as[k4*4+1] * v.y + cs[k4*4+1], 0.f);
            v.z = fmaxf(as[k4*4+2] * v.z + cs[k4*4+2], 0.f);
            v.w = fmaxf(as[k4*4+3] * v.w + cs[k4*4+3], 0.f);
        }
        xs[r * 65 + k4 * 4 + 0] = v.x;
        xs[r * 65 + k4 * 4 + 1] = v.y;
        xs[r * 65 + k4 * 4 + 2] = v.z;
        xs[r * 65 + k4 * 4 + 3] = v.w;
    }
    __syncthreads();
    int c4 = tid & 3, r = tid >> 2;
    float4 acc = ((const float4*)b2b)[c4];
    const float* xr = xs + r * 65;
    #pragma unroll 8
    for (int k = 0; k < 64; ++k) {
        float4 wv = ws[k * 4 + c4];
        fma4(acc, xr[k], wv);
    }
    int row = row0 + r;
    if (row < n) {
        int g = batch[row];
        if (c4 == 0) atomicAdd(&cl[g], 1.f);
        float* pp = &pl[g * 16 + c4 * 4];
        atomicAdd(pp + 0, acc.x); atomicAdd(pp + 1, acc.y);
        atomicAdd(pp + 2, acc.z); atomicAdd(pp + 3, acc.w);
    }
    __syncthreads();
    if (tid < 64 && cl[tid] != 0.f) atomicAdd(&cnt[tid], cl[tid]);
    for (int i = tid; i < G_GRAPHS * 16; i += 256) {
        int g = i >> 4;
        if (cl[g] != 0.f) atomicAdd(&pool[i], pl[i]);
    }
}

// ---------------- head ----------------
__global__ void k_head(const float* __restrict__ pool, const float* __restrict__ cnt,
                       const float* __restrict__ lw, const float* __restrict__ lb,
                       float* __restrict__ out)
{
    int g = threadIdx.x;
    float cv = fmaxf(cnt[g], 1.0f);
    float acc = lb[0];
    #pragma unroll
    for (int f = 0; f < 16; ++f) acc += (pool[g * 16 + f] / cv) * lw[f];
    out[g] = 1.0f / (1.0f + expf(-acc));
}

extern "C" void kernel_launch(void* const* d_in, const int* in_sizes, int n_in,
                              void* d_out, int out_size, void* d_ws, size_t ws_size,
                              hipStream_t stream)
{
    const float* x    = (const float*)d_in[0];
    const int*   eidx = (const int*)d_in[1];
    const int*   batch= (const int*)d_in[2];
    const float* eps1 = (const float*)d_in[3];
    const float* eps2 = (const float*)d_in[4];
    const float* w1a  = (const float*)d_in[5];
    const float* b1a  = (const float*)d_in[6];
    const float* g1   = (const float*)d_in[7];
    const float* bt1  = (const float*)d_in[8];
    const float* w1b  = (const float*)d_in[9];
    const float* b1b  = (const float*)d_in[10];
    const float* w2a  = (const float*)d_in[11];
    const float* b2a  = (const float*)d_in[12];
    const float* g2   = (const float*)d_in[13];
    const float* bt2  = (const float*)d_in[14];
    const float* w2b  = (const float*)d_in[15];
    const float* b2b  = (const float*)d_in[16];
    const float* lw   = (const float*)d_in[17];
    const float* lb   = (const float*)d_in[18];
    float* out = (float*)d_out;

    int n  = in_sizes[0] / 128;
    int nE = in_sizes[1] / 2;
    const int* srcI = eidx;
    const int* dstI = eidx + nE;
    int vec4ok = ((nE & 3) == 0) && ((((uintptr_t)eidx) & 15) == 0);

    char* wsb = (char*)d_ws;
    size_t nn = (size_t)n;
    unsigned int* y8  = (unsigned int*)wsb;             // n*64 fp8
    __half* h1        = (__half*)(wsb + nn * 64);       // n*64 fp16 (reused as h3)
    unsigned int* h28 = (unsigned int*)(wsb + nn * 192);// n*32 fp8
    __half* agg2h     = (__half*)(wsb + nn * 224);      // n*32 fp16
    __half* h3        = h1;                              // alias (h1 dead after mlp1b)
    float* stats = (float*)(wsb + nn * 288);
    float* a1     = stats;          float* c1     = stats + 64;
    float* a2     = stats + 128;    float* c2     = stats + 192;
    float* pool   = stats + 256;    float* cntb   = stats + 1280;
    float* p_sum1 = stats + 1344;   float* p_sq1  = stats + 5440;
    float* p_sum2 = stats + 9536;   float* p_sq2  = stats + 13632;
    // stats region total: 17728 floats

    int cblocks = (nE + C_CHUNK - 1) / C_CHUNK;   // must be <= 256
    int nbins   = (n + BIN_SIZE - 1) >> BIN_SHIFT;

    int* off     = (int*)(stats + 17728);       // n+1
    int* csr     = off + (n + 1);               // nE
    int* binCnt  = csr + nE;                    // NBINS_CAP+1
    int* binOff  = binCnt + NBINS_CAP + 1;      // NBINS_CAP+1
    int* staging = binOff + NBINS_CAP + 1;      // nE
    int* hist    = staging + nE;                // cblocks * nbins

    hipMemsetAsync(stats + 256, 0, (17728 - 256) * sizeof(float), stream);

    int tiles64  = (n + 63) / 64;
    int tiles128 = (n + 127) / 128;
    int nblocks4 = (n + 3) / 4;

    k_g1A<<<tiles64 + cblocks, 256, 0, stream>>>(x, w1a, y8, n, tiles64,
                                                 dstI, hist, nE, nbins, vec4ok);
    k_binB1<<<nbins, 256, 0, stream>>>(hist, cblocks, nbins, binCnt);
    k_binB2<<<1, 1024, 0, stream>>>(binCnt, nbins, nE, binOff, off, n);
    k_binC2<<<cblocks, 256, 0, stream>>>(srcI, dstI, binOff, hist, staging, nE, nbins, vec4ok);
    k_binD<<<nbins, 256, 0, stream>>>(binOff, staging, off, csr, n);

    k_agg1<<<nblocks4, 256, 0, stream>>>(y8, off, csr, b1a, eps1, h1, n, p_sum1, p_sq1);
    k_bnfin<<<1, 64, 0, stream>>>(p_sum1, p_sq1, g1, bt1, (float)n, a1, c1);
    k_mlp1b<<<tiles128, 256, 0, stream>>>(h1, a1, c1, w1b, b1b, h28, n);
    k_agg2<<<nblocks4, 256, 0, stream>>>(h28, off, csr, eps2, agg2h, n);
    k_gemm2<<<tiles64, 256, 0, stream>>>(agg2h, w2a, b2a, h3, n, p_sum2, p_sq2);
    k_bnfin<<<1, 64, 0, stream>>>(p_sum2, p_sq2, g2, bt2, (float)n, a2, c2);
    k_final<<<tiles64, 256, 0, stream>>>(h3, a2, c2, w2b, b2b, batch, pool, cntb, n);
    k_head<<<1, 64, 0, stream>>>(pool, cntb, lw, lb, out);
}